// Round 1
// baseline (369.164 us; speedup 1.0000x reference)
//
#include <hip/hip_runtime.h>
#include <hip/hip_bf16.h>
#include <stdint.h>

typedef unsigned short u16;
typedef __attribute__((ext_vector_type(8))) short bf16x8;
typedef __attribute__((ext_vector_type(4))) float f32x4;

#define SEQ   2048
#define BATCH 4
#define NTOK  (BATCH * SEQ)   // 8192

__device__ __forceinline__ u16 f2bf(float f) {
  union { float f; uint32_t u; } c{f};
  uint32_t r = c.u + 0x7fffu + ((c.u >> 16) & 1u);   // RNE
  return (u16)(r >> 16);
}

__device__ __forceinline__ void gll16(const void* g, void* l) {
  __builtin_amdgcn_global_load_lds((const __attribute__((address_space(1))) void*)g,
                                   (__attribute__((address_space(3))) void*)l,
                                   16, 0, 0);
}

// ---------------- fp32 -> bf16 elementwise (x) ----------------
__global__ __launch_bounds__(256) void k_cvt(const float* __restrict__ in,
                                             u16* __restrict__ out) {
  int i = (blockIdx.x * 256 + threadIdx.x) * 8;
  float4 a = *(const float4*)(in + i);
  float4 b = *(const float4*)(in + i + 4);
  union { u16 u[8]; bf16x8 v; } r;
  r.u[0] = f2bf(a.x); r.u[1] = f2bf(a.y); r.u[2] = f2bf(a.z); r.u[3] = f2bf(a.w);
  r.u[4] = f2bf(b.x); r.u[5] = f2bf(b.y); r.u[6] = f2bf(b.z); r.u[7] = f2bf(b.w);
  *(bf16x8*)(out + i) = r.v;
}

// ------------- fp32 [K][N] -> bf16 [N][K] transpose -------------
__global__ __launch_bounds__(256) void k_cvtT(const float* __restrict__ in,
                                              u16* __restrict__ out, int K, int N) {
  __shared__ float tl[32][33];
  int tx = threadIdx.x & 31, ty = threadIdx.x >> 5;
  int c0 = blockIdx.x * 32, r0 = blockIdx.y * 32;
#pragma unroll
  for (int j = 0; j < 32; j += 8)
    tl[ty + j][tx] = in[(size_t)(r0 + ty + j) * N + c0 + tx];
  __syncthreads();
#pragma unroll
  for (int j = 0; j < 32; j += 8)
    out[(size_t)(c0 + ty + j) * K + r0 + tx] = f2bf(tl[tx][ty + j]);
}

// ---------------- bf16 GEMM: C = A[M][K] * BT[N][K]^T + bias ----------------
// 128x128 tile, BK=32, 4 waves, global_load_lds staging (m97 structure).
template<int OUT_BF16>
__global__ __launch_bounds__(256) void k_gemm(const u16* __restrict__ A,
                                              const u16* __restrict__ BT,
                                              const float* __restrict__ bias,
                                              void* __restrict__ Cv, int N, int K) {
  __shared__ alignas(16) u16 As[128 * 32];
  __shared__ alignas(16) u16 Bs[128 * 32];
  const int t = threadIdx.x, l = t & 63, w = t >> 6;
  const int brow = blockIdx.y * 128, bcol = blockIdx.x * 128;
  const int wr = w >> 1, wc = w & 1;
  f32x4 acc[4][4] = {};
  const u16* gA = A + (size_t)(brow + (t >> 2)) * K + (t & 3) * 8;
  const u16* gB = BT + (size_t)(bcol + (t >> 2)) * K + (t & 3) * 8;
  char* lA = (char*)As + w * 1024;
  char* lB = (char*)Bs + w * 1024;
  const int ro = (l & 15) * 64, ko = (l >> 4) * 16;   // byte offsets in LDS row / k
  for (int k0 = 0; k0 < K; k0 += 32) {
    gll16(gA + k0, lA);
    gll16(gA + (size_t)64 * K + k0, lA + 4096);
    gll16(gB + k0, lB);
    gll16(gB + (size_t)64 * K + k0, lB + 4096);
    __syncthreads();
    bf16x8 af[4], bff[4];
#pragma unroll
    for (int mi = 0; mi < 4; mi++)
      af[mi] = *(const bf16x8*)((const char*)As + (wr * 64 + mi * 16) * 64 + ro + ko);
#pragma unroll
    for (int ni = 0; ni < 4; ni++)
      bff[ni] = *(const bf16x8*)((const char*)Bs + (wc * 64 + ni * 16) * 64 + ro + ko);
#pragma unroll
    for (int mi = 0; mi < 4; mi++)
#pragma unroll
      for (int ni = 0; ni < 4; ni++)
        acc[mi][ni] = __builtin_amdgcn_mfma_f32_16x16x32_bf16(af[mi], bff[ni], acc[mi][ni], 0, 0, 0);
    __syncthreads();
  }
  const int r0 = brow + wr * 64 + (l >> 4) * 4;
  const int c0 = bcol + wc * 64 + (l & 15);
#pragma unroll
  for (int ni = 0; ni < 4; ni++) {
    float bv = bias[c0 + ni * 16];
#pragma unroll
    for (int mi = 0; mi < 4; mi++)
#pragma unroll
      for (int r = 0; r < 4; r++) {
        float v = acc[mi][ni][r] + bv;
        size_t off = (size_t)(r0 + mi * 16 + r) * N + c0 + ni * 16;
        if (OUT_BF16) ((u16*)Cv)[off] = f2bf(v);
        else          ((float*)Cv)[off] = v;
      }
  }
}

// -------- transpose V slice of qkv -> vT[bh][d][n] (bf16) --------
__global__ __launch_bounds__(256) void k_trV(const u16* __restrict__ qkv,
                                             u16* __restrict__ vT) {
  __shared__ u16 s[32][33];
  int tx = threadIdx.x & 31, ty = threadIdx.x >> 5;
  int n0 = blockIdx.x * 32, d0 = blockIdx.y * 32, bh = blockIdx.z;
  int b = bh >> 4, h = bh & 15;
#pragma unroll
  for (int j = 0; j < 32; j += 8)
    s[ty + j][tx] = qkv[(size_t)(b * SEQ + n0 + ty + j) * 3072 + 2048 + h * 64 + d0 + tx];
  __syncthreads();
#pragma unroll
  for (int j = 0; j < 32; j += 8)
    vT[(size_t)(bh * 64 + d0 + ty + j) * SEQ + n0 + tx] = s[tx][ty + j];
}

// ---------------- causal flash attention ----------------
// grid (qt=16, h=16, b=4); 256 thr = 4 waves; Q-tile 128 (32 rows/wave); KV-tile 64.
__global__ __launch_bounds__(256) void k_attn(const u16* __restrict__ qkv,
                                              const u16* __restrict__ vT,
                                              u16* __restrict__ outp) {
  __shared__ alignas(16) char Ks[8192];    // K tile [64 k][64 d], swizzled
  __shared__ alignas(16) char Vs[8192];    // V^T tile [64 d][64 k], swizzled
  __shared__ alignas(16) char Ps[16384];   // per-wave P [32 q][64 k], swizzled
  const int t = threadIdx.x, l = t & 63, w = t >> 6;
  const int qt = blockIdx.x, h = blockIdx.y, b = blockIdx.z;
  const int bh = b * 16 + h;
  const int qr0 = qt * 128 + w * 32;
  const int lg = l >> 4, lr = l & 15;

  bf16x8 qf[2][2];
#pragma unroll
  for (int mi = 0; mi < 2; mi++)
#pragma unroll
    for (int ks = 0; ks < 2; ks++)
      qf[mi][ks] = *(const bf16x8*)(qkv + (size_t)(b * SEQ + qr0 + mi * 16 + lr) * 3072
                                    + h * 64 + ks * 32 + lg * 8);
  f32x4 o[2][4] = {};
  float m_run[2][4], l_run[2][4];
#pragma unroll
  for (int mi = 0; mi < 2; mi++)
#pragma unroll
    for (int r = 0; r < 4; r++) { m_run[mi][r] = -1e30f; l_run[mi][r] = 0.f; }

  const int nkv = 2 * qt + 2;
  const int srow = t >> 3;               // staging row (0..31), +32 for 2nd half
  const int csw = ((t & 7) * 16) ^ ((srow & 7) << 4);  // swizzled source byte-col
  char* lK = Ks + w * 1024;
  char* lV = Vs + w * 1024;
  char* Pw = Ps + w * 4096;

  for (int j = 0; j < nkv; j++) {
    const int kv0 = j * 64;
    // stage K + V^T (linear LDS dest, inverse-swizzled global source)
    gll16(qkv + (size_t)(b * SEQ + kv0 + srow) * 3072 + 1024 + h * 64 + (csw >> 1), lK);
    gll16(qkv + (size_t)(b * SEQ + kv0 + srow + 32) * 3072 + 1024 + h * 64 + (csw >> 1), lK + 4096);
    gll16(vT + (size_t)(bh * 64 + srow) * SEQ + kv0 + (csw >> 1), lV);
    gll16(vT + (size_t)(bh * 64 + srow + 32) * SEQ + kv0 + (csw >> 1), lV + 4096);
    __syncthreads();

    const bool active = (kv0 <= qr0 + 31);   // tile fully above diagonal for this wave -> skip
    if (active) {
      // ---- S = Q K^T ----
      f32x4 s[2][4] = {};
#pragma unroll
      for (int ks = 0; ks < 2; ks++) {
        bf16x8 kf[4];
#pragma unroll
        for (int ni = 0; ni < 4; ni++) {
          int kidx = ni * 16 + lr;
          kf[ni] = *(const bf16x8*)(Ks + kidx * 128 + ((ks * 64 + lg * 16) ^ ((kidx & 7) << 4)));
        }
#pragma unroll
        for (int mi = 0; mi < 2; mi++)
#pragma unroll
          for (int ni = 0; ni < 4; ni++)
            s[mi][ni] = __builtin_amdgcn_mfma_f32_16x16x32_bf16(qf[mi][ks], kf[ni], s[mi][ni], 0, 0, 0);
      }
      // ---- scale + causal mask ----
      const bool need_mask = (kv0 + 63 > qr0);
#pragma unroll
      for (int mi = 0; mi < 2; mi++)
#pragma unroll
        for (int ni = 0; ni < 4; ni++)
#pragma unroll
          for (int r = 0; r < 4; r++) {
            float v = s[mi][ni][r] * 0.125f;
            if (need_mask) {
              int qg = qr0 + mi * 16 + lg * 4 + r;
              int kg = kv0 + ni * 16 + lr;
              if (kg > qg) v = -1e30f;
            }
            s[mi][ni][r] = v;
          }
      // ---- online softmax (16-lane shuffle reduce) ----
#pragma unroll
      for (int mi = 0; mi < 2; mi++)
#pragma unroll
        for (int r = 0; r < 4; r++) {
          float v = fmaxf(fmaxf(s[mi][0][r], s[mi][1][r]), fmaxf(s[mi][2][r], s[mi][3][r]));
          v = fmaxf(v, __shfl_xor(v, 1));
          v = fmaxf(v, __shfl_xor(v, 2));
          v = fmaxf(v, __shfl_xor(v, 4));
          v = fmaxf(v, __shfl_xor(v, 8));
          float mold = m_run[mi][r];
          float mnew = fmaxf(mold, v);
          float corr = __expf(mold - mnew);
          m_run[mi][r] = mnew;
          float rs = 0.f;
#pragma unroll
          for (int ni = 0; ni < 4; ni++) {
            float p = __expf(s[mi][ni][r] - mnew);
            s[mi][ni][r] = p;
            rs += p;
          }
          rs += __shfl_xor(rs, 1);
          rs += __shfl_xor(rs, 2);
          rs += __shfl_xor(rs, 4);
          rs += __shfl_xor(rs, 8);
          l_run[mi][r] = l_run[mi][r] * corr + rs;
#pragma unroll
          for (int ni = 0; ni < 4; ni++) o[mi][ni][r] *= corr;
        }
      // ---- P -> LDS (bf16, swizzled) ----
#pragma unroll
      for (int mi = 0; mi < 2; mi++)
#pragma unroll
        for (int ni = 0; ni < 4; ni++)
#pragma unroll
          for (int r = 0; r < 4; r++) {
            int q = mi * 16 + lg * 4 + r;
            int kb = (ni * 16 + lr) * 2;
            *(u16*)(Pw + q * 128 + (kb ^ ((q & 7) << 4))) = f2bf(s[mi][ni][r]);
          }
      asm volatile("s_waitcnt lgkmcnt(0)" ::: "memory");
      // ---- O += P V ----
#pragma unroll
      for (int ks = 0; ks < 2; ks++) {
        bf16x8 pa[2], vf[4];
#pragma unroll
        for (int mi = 0; mi < 2; mi++) {
          int q = mi * 16 + lr;
          pa[mi] = *(const bf16x8*)(Pw + q * 128 + ((ks * 64 + lg * 16) ^ ((q & 7) << 4)));
        }
#pragma unroll
        for (int ni = 0; ni < 4; ni++) {
          int dd = ni * 16 + lr;
          vf[ni] = *(const bf16x8*)(Vs + dd * 128 + ((ks * 64 + lg * 16) ^ ((dd & 7) << 4)));
        }
#pragma unroll
        for (int mi = 0; mi < 2; mi++)
#pragma unroll
          for (int ni = 0; ni < 4; ni++)
            o[mi][ni] = __builtin_amdgcn_mfma_f32_16x16x32_bf16(pa[mi], vf[ni], o[mi][ni], 0, 0, 0);
      }
    }
    __syncthreads();
  }
  // ---- epilogue: O / l, store bf16 [tok][h*64+d] ----
#pragma unroll
  for (int mi = 0; mi < 2; mi++)
#pragma unroll
    for (int r = 0; r < 4; r++) {
      float inv = 1.0f / l_run[mi][r];
      int qg = qr0 + mi * 16 + lg * 4 + r;
#pragma unroll
      for (int ni = 0; ni < 4; ni++)
        outp[(size_t)(b * SEQ + qg) * 1024 + h * 64 + ni * 16 + lr] = f2bf(o[mi][ni][r] * inv);
    }
}

extern "C" void kernel_launch(void* const* d_in, const int* in_sizes, int n_in,
                              void* d_out, int out_size, void* d_ws, size_t ws_size,
                              hipStream_t stream) {
  const float* x     = (const float*)d_in[0];
  const float* w_qkv = (const float*)d_in[1];
  const float* b_qkv = (const float*)d_in[2];
  const float* w_out = (const float*)d_in[3];
  const float* b_out = (const float*)d_in[4];

  char* ws = (char*)d_ws;
  u16* xbf   = (u16*)(ws);                       // 16 MB [8192][1024]  (reused as attn_out)
  u16* wqkvT = (u16*)(ws + (16u << 20));         //  6 MB [3072][1024]
  u16* woutT = (u16*)(ws + (22u << 20));         //  2 MB [1024][1024]
  u16* qkvb  = (u16*)(ws + (24u << 20));         // 48 MB [8192][3072]
  u16* vTb   = (u16*)(ws + (72u << 20));         // 16 MB [64][64][2048]

  k_cvt <<<4096, 256, 0, stream>>>(x, xbf);
  k_cvtT<<<dim3(96, 32), 256, 0, stream>>>(w_qkv, wqkvT, 1024, 3072);
  k_cvtT<<<dim3(32, 32), 256, 0, stream>>>(w_out, woutT, 1024, 1024);
  k_gemm<1><<<dim3(24, 64), 256, 0, stream>>>(xbf, wqkvT, b_qkv, (void*)qkvb, 3072, 1024);
  k_trV <<<dim3(64, 2, 64), 256, 0, stream>>>(qkvb, vTb);
  k_attn<<<dim3(16, 16, 4), 256, 0, stream>>>(qkvb, vTb, xbf);
  k_gemm<0><<<dim3(8, 64), 256, 0, stream>>>(xbf, woutT, b_out, d_out, 1024, 1024);
}

// Round 2
// 224.194 us; speedup vs baseline: 1.6466x; 1.6466x over previous
//
#include <hip/hip_runtime.h>
#include <hip/hip_bf16.h>
#include <stdint.h>

typedef unsigned short u16;
typedef __attribute__((ext_vector_type(8))) short bf16x8;
typedef __attribute__((ext_vector_type(4))) float f32x4;
typedef __attribute__((ext_vector_type(16))) float f32x16;
typedef __attribute__((ext_vector_type(4))) short s16x4;

#define SEQ   2048
#define BATCH 4

#define MFMA16(a,b,c) __builtin_amdgcn_mfma_f32_16x16x32_bf16(a,b,c,0,0,0)
#define MFMA32(a,b,c) __builtin_amdgcn_mfma_f32_32x32x16_bf16(a,b,c,0,0,0)
#define EXP2F __builtin_amdgcn_exp2f

__device__ __forceinline__ u16 f2bf(float f) {
  union { float f; uint32_t u; } c{f};
  uint32_t r = c.u + 0x7fffu + ((c.u >> 16) & 1u);   // RNE
  return (u16)(r >> 16);
}

__device__ __forceinline__ void gll16(const void* g, void* l) {
  __builtin_amdgcn_global_load_lds((const __attribute__((address_space(1))) void*)g,
                                   (__attribute__((address_space(3))) void*)l,
                                   16, 0, 0);
}

// ---------------- fp32 -> bf16 elementwise (x) ----------------
__global__ __launch_bounds__(256) void k_cvt(const float* __restrict__ in,
                                             u16* __restrict__ out) {
  int i = (blockIdx.x * 256 + threadIdx.x) * 8;
  float4 a = *(const float4*)(in + i);
  float4 b = *(const float4*)(in + i + 4);
  union { u16 u[8]; bf16x8 v; } r;
  r.u[0] = f2bf(a.x); r.u[1] = f2bf(a.y); r.u[2] = f2bf(a.z); r.u[3] = f2bf(a.w);
  r.u[4] = f2bf(b.x); r.u[5] = f2bf(b.y); r.u[6] = f2bf(b.z); r.u[7] = f2bf(b.w);
  *(bf16x8*)(out + i) = r.v;
}

// ------------- fp32 [K][N] -> bf16 [N][K] transpose -------------
__global__ __launch_bounds__(256) void k_cvtT(const float* __restrict__ in,
                                              u16* __restrict__ out, int K, int N) {
  __shared__ float tl[32][33];
  int tx = threadIdx.x & 31, ty = threadIdx.x >> 5;
  int c0 = blockIdx.x * 32, r0 = blockIdx.y * 32;
#pragma unroll
  for (int j = 0; j < 32; j += 8)
    tl[ty + j][tx] = in[(size_t)(r0 + ty + j) * N + c0 + tx];
  __syncthreads();
#pragma unroll
  for (int j = 0; j < 32; j += 8)
    out[(size_t)(c0 + ty + j) * K + r0 + tx] = f2bf(tl[tx][ty + j]);
}

// ---------------- bf16 GEMM: C = A[M][K] * BT[N][K]^T + bias ----------------
template<int OUT_BF16>
__global__ __launch_bounds__(256) void k_gemm(const u16* __restrict__ A,
                                              const u16* __restrict__ BT,
                                              const float* __restrict__ bias,
                                              void* __restrict__ Cv, int N, int K) {
  __shared__ alignas(16) u16 As[128 * 32];
  __shared__ alignas(16) u16 Bs[128 * 32];
  const int t = threadIdx.x, l = t & 63, w = t >> 6;
  const int brow = blockIdx.y * 128, bcol = blockIdx.x * 128;
  const int wr = w >> 1, wc = w & 1;
  f32x4 acc[4][4] = {};
  const u16* gA = A + (size_t)(brow + (t >> 2)) * K + (t & 3) * 8;
  const u16* gB = BT + (size_t)(bcol + (t >> 2)) * K + (t & 3) * 8;
  char* lA = (char*)As + w * 1024;
  char* lB = (char*)Bs + w * 1024;
  const int ro = (l & 15) * 64, ko = (l >> 4) * 16;
  for (int k0 = 0; k0 < K; k0 += 32) {
    gll16(gA + k0, lA);
    gll16(gA + (size_t)64 * K + k0, lA + 4096);
    gll16(gB + k0, lB);
    gll16(gB + (size_t)64 * K + k0, lB + 4096);
    __syncthreads();
    bf16x8 af[4], bff[4];
#pragma unroll
    for (int mi = 0; mi < 4; mi++)
      af[mi] = *(const bf16x8*)((const char*)As + (wr * 64 + mi * 16) * 64 + ro + ko);
#pragma unroll
    for (int ni = 0; ni < 4; ni++)
      bff[ni] = *(const bf16x8*)((const char*)Bs + (wc * 64 + ni * 16) * 64 + ro + ko);
#pragma unroll
    for (int mi = 0; mi < 4; mi++)
#pragma unroll
      for (int ni = 0; ni < 4; ni++)
        acc[mi][ni] = MFMA16(af[mi], bff[ni], acc[mi][ni]);
    __syncthreads();
  }
  const int r0 = brow + wr * 64 + (l >> 4) * 4;
  const int c0 = bcol + wc * 64 + (l & 15);
#pragma unroll
  for (int ni = 0; ni < 4; ni++) {
    float bv = bias[c0 + ni * 16];
#pragma unroll
    for (int mi = 0; mi < 4; mi++)
#pragma unroll
      for (int r = 0; r < 4; r++) {
        float v = acc[mi][ni][r] + bv;
        size_t off = (size_t)(r0 + mi * 16 + r) * N + c0 + ni * 16;
        if (OUT_BF16) ((u16*)Cv)[off] = f2bf(v);
        else          ((float*)Cv)[off] = v;
      }
  }
}

// -------- transpose V slice of qkv -> vT[bh][d][n] (bf16) --------
__global__ __launch_bounds__(256) void k_trV(const u16* __restrict__ qkv,
                                             u16* __restrict__ vT) {
  __shared__ u16 s[32][33];
  int tx = threadIdx.x & 31, ty = threadIdx.x >> 5;
  int n0 = blockIdx.x * 32, d0 = blockIdx.y * 32, bh = blockIdx.z;
  int b = bh >> 4, h = bh & 15;
#pragma unroll
  for (int j = 0; j < 32; j += 8)
    s[ty + j][tx] = qkv[(size_t)(b * SEQ + n0 + ty + j) * 3072 + 2048 + h * 64 + d0 + tx];
  __syncthreads();
#pragma unroll
  for (int j = 0; j < 32; j += 8)
    vT[(size_t)(bh * 64 + d0 + ty + j) * SEQ + n0 + tx] = s[tx][ty + j];
}

// ---------------- causal flash attention, v2 ----------------
// Swapped-operand 32x32 MFMA: S^T = K.Q^T so C-col = q = lane&31 -> softmax is
// lane-local (+1 shfl_xor(32)). O^T = V^T.P^T keeps q on the col axis.
// Work balance: block handles Q-tiles (qp, 15-qp) sequentially -> 34 KV-iters/block.
// grid (qp=8, h=16, b=4); 256 thr = 4 waves; Q-tile 128 (32 rows/wave); KV-tile 64.
__global__ __launch_bounds__(256) void k_attn(const u16* __restrict__ qkv,
                                              const u16* __restrict__ vT,
                                              u16* __restrict__ outp) {
  __shared__ alignas(16) char Ks[8192];    // K tile [64 k][64 d], swizzled rows
  __shared__ alignas(16) char Vs[8192];    // V^T tile [64 d][64 k], swizzled rows
  const int t = threadIdx.x, l = t & 63, w = t >> 6;
  const int hi = l >> 5, q = l & 31;
  const int qp = blockIdx.x, h = blockIdx.y, b = blockIdx.z;
  const int bh = b * 16 + h;
  const int srow = t >> 3;                              // staging row 0..31
  const int csw = ((t & 7) * 16) ^ ((srow & 7) << 4);   // pre-swizzled source col
  char* lK = Ks + w * 1024;
  char* lV = Vs + w * 1024;
  const int swz = (q & 7) << 4;                         // read-side XOR (row&7 == q&7 for row and row+32)
  const float SC = 0.18033688011112042f;                // 0.125 * log2(e)

  for (int tsel = 0; tsel < 2; tsel++) {
    const int qt = tsel ? (15 - qp) : qp;
    const int qr0 = qt * 128 + w * 32;
    const int qg = qr0 + q;
    bf16x8 qf[4];
#pragma unroll
    for (int c = 0; c < 4; c++)
      qf[c] = *(const bf16x8*)(qkv + (size_t)(b * SEQ + qg) * 3072 + h * 64 + c * 16 + hi * 8);
    f32x16 o0 = {}, o1 = {};
    float m_run = -1e30f, l_run = 0.f;
    const int nkv = 2 * qt + 2;

    for (int j = 0; j < nkv; j++) {
      const int kv0 = j * 64;
      gll16(qkv + (size_t)(b * SEQ + kv0 + srow) * 3072 + 1024 + h * 64 + (csw >> 1), lK);
      gll16(qkv + (size_t)(b * SEQ + kv0 + srow + 32) * 3072 + 1024 + h * 64 + (csw >> 1), lK + 4096);
      gll16(vT + (size_t)(bh * 64 + srow) * SEQ + kv0 + (csw >> 1), lV);
      gll16(vT + (size_t)(bh * 64 + srow + 32) * SEQ + kv0 + (csw >> 1), lV + 4096);
      __syncthreads();

      if (kv0 <= qr0 + 31) {
        // ---- S^T = K . Q^T : st0 covers k in [kv0, kv0+32), st1 [kv0+32, kv0+64) ----
        f32x16 st0 = {}, st1 = {};
#pragma unroll
        for (int c = 0; c < 4; c++) {
          const int cb = c * 32 + hi * 16;
          bf16x8 k0 = *(const bf16x8*)(Ks + q * 128 + (cb ^ swz));
          bf16x8 k1 = *(const bf16x8*)(Ks + (32 + q) * 128 + (cb ^ swz));
          st0 = MFMA32(k0, qf[c], st0);
          st1 = MFMA32(k1, qf[c], st1);
        }
        // ---- scale (exp2 domain) + causal mask + lane-local max ----
        const bool nm = (kv0 + 63 > qr0);
        float vmax = -1e30f;
#pragma unroll
        for (int r = 0; r < 16; r++) {
          const int krow = (r & 3) + 8 * (r >> 2) + 4 * hi;
          float s0 = st0[r] * SC, s1 = st1[r] * SC;
          if (nm) {
            if (kv0 + krow > qg)      s0 = -1e30f;
            if (kv0 + 32 + krow > qg) s1 = -1e30f;
          }
          st0[r] = s0; st1[r] = s1;
          vmax = fmaxf(vmax, fmaxf(s0, s1));
        }
        vmax = fmaxf(vmax, __shfl_xor(vmax, 32));
        const float mnew = fmaxf(m_run, vmax);
        const float corr = EXP2F(m_run - mnew);
        m_run = mnew;
        float rsum = 0.f;
#pragma unroll
        for (int r = 0; r < 16; r++) {
          float p0 = EXP2F(st0[r] - mnew);
          float p1 = EXP2F(st1[r] - mnew);
          st0[r] = p0; st1[r] = p1;
          rsum += p0 + p1;
        }
        rsum += __shfl_xor(rsum, 32);
        l_run = l_run * corr + rsum;
#pragma unroll
        for (int r = 0; r < 16; r++) { o0[r] *= corr; o1[r] *= corr; }

        // ---- P^T -> bf16 B-frags (cvt_pk + half-wave exchange), then O^T += V^T.P^T ----
#pragma unroll
        for (int khb = 0; khb < 2; khb++) {
          uint32_t pk[8], ot[8];
#pragma unroll
          for (int ii = 0; ii < 8; ii++) {
            float lo = khb ? st1[2 * ii] : st0[2 * ii];
            float hf = khb ? st1[2 * ii + 1] : st0[2 * ii + 1];
            asm("v_cvt_pk_bf16_f32 %0, %1, %2" : "=v"(pk[ii]) : "v"(lo), "v"(hf));
          }
#pragma unroll
          for (int ii = 0; ii < 8; ii++) ot[ii] = (uint32_t)__shfl_xor((int)pk[ii], 32);
          union { uint32_t u[4]; bf16x8 v; } be, bo;
          be.u[0] = hi ? ot[2] : pk[0];
          be.u[1] = hi ? ot[3] : pk[1];
          be.u[2] = hi ? pk[2] : ot[0];
          be.u[3] = hi ? pk[3] : ot[1];
          bo.u[0] = hi ? ot[6] : pk[4];
          bo.u[1] = hi ? ot[7] : pk[5];
          bo.u[2] = hi ? pk[6] : ot[4];
          bo.u[3] = hi ? pk[7] : ot[5];
#pragma unroll
          for (int kti = 0; kti < 2; kti++) {
            const int cb = (khb * 2 + kti) * 32 + hi * 16;
            bf16x8 v0 = *(const bf16x8*)(Vs + q * 128 + (cb ^ swz));
            bf16x8 v1 = *(const bf16x8*)(Vs + (32 + q) * 128 + (cb ^ swz));
            bf16x8 pb = kti ? bo.v : be.v;
            o0 = MFMA32(v0, pb, o0);
            o1 = MFMA32(v1, pb, o1);
          }
        }
      }
      __syncthreads();
    }
    // ---- epilogue: O^T columns are lane-local rows; pack 4 bf16 per store ----
    const float invl = 1.0f / l_run;
#pragma unroll
    for (int dh = 0; dh < 2; dh++)
#pragma unroll
      for (int jq = 0; jq < 4; jq++) {
        union { u16 u[4]; s16x4 v; } pk4;
#pragma unroll
        for (int r = 0; r < 4; r++)
          pk4.u[r] = f2bf((dh ? o1[4 * jq + r] : o0[4 * jq + r]) * invl);
        *(s16x4*)(outp + (size_t)(b * SEQ + qg) * 1024 + h * 64 + dh * 32 + jq * 8 + hi * 4) = pk4.v;
      }
  }
}

extern "C" void kernel_launch(void* const* d_in, const int* in_sizes, int n_in,
                              void* d_out, int out_size, void* d_ws, size_t ws_size,
                              hipStream_t stream) {
  const float* x     = (const float*)d_in[0];
  const float* w_qkv = (const float*)d_in[1];
  const float* b_qkv = (const float*)d_in[2];
  const float* w_out = (const float*)d_in[3];
  const float* b_out = (const float*)d_in[4];

  char* ws = (char*)d_ws;
  u16* xbf   = (u16*)(ws);                       // 16 MB [8192][1024]  (reused as attn_out)
  u16* wqkvT = (u16*)(ws + (16u << 20));         //  6 MB [3072][1024]
  u16* woutT = (u16*)(ws + (22u << 20));         //  2 MB [1024][1024]
  u16* qkvb  = (u16*)(ws + (24u << 20));         // 48 MB [8192][3072]
  u16* vTb   = (u16*)(ws + (72u << 20));         // 16 MB [64][64][2048]

  k_cvt <<<4096, 256, 0, stream>>>(x, xbf);
  k_cvtT<<<dim3(96, 32), 256, 0, stream>>>(w_qkv, wqkvT, 1024, 3072);
  k_cvtT<<<dim3(32, 32), 256, 0, stream>>>(w_out, woutT, 1024, 1024);
  k_gemm<1><<<dim3(24, 64), 256, 0, stream>>>(xbf, wqkvT, b_qkv, (void*)qkvb, 3072, 1024);
  k_trV <<<dim3(64, 2, 64), 256, 0, stream>>>(qkvb, vTb);
  k_attn<<<dim3(8, 16, 4), 256, 0, stream>>>(qkvb, vTb, xbf);
  k_gemm<0><<<dim3(8, 64), 256, 0, stream>>>(xbf, woutT, b_out, d_out, 1024, 1024);
}

// Round 6
// 214.217 us; speedup vs baseline: 1.7233x; 1.0466x over previous
//
#include <hip/hip_runtime.h>
#include <hip/hip_bf16.h>
#include <stdint.h>

typedef unsigned short u16;
typedef __attribute__((ext_vector_type(8))) short bf16x8;
typedef __attribute__((ext_vector_type(4))) float f32x4;
typedef __attribute__((ext_vector_type(16))) float f32x16;
typedef __attribute__((ext_vector_type(4))) short s16x4;

#define SEQ   2048
#define BATCH 4

#define MFMA16(a,b,c) __builtin_amdgcn_mfma_f32_16x16x32_bf16(a,b,c,0,0,0)
#define MFMA32(a,b,c) __builtin_amdgcn_mfma_f32_32x32x16_bf16(a,b,c,0,0,0)
#define EXP2F __builtin_amdgcn_exp2f

__device__ __forceinline__ u16 f2bf(float f) {
  union { float f; uint32_t u; } c{f};
  uint32_t r = c.u + 0x7fffu + ((c.u >> 16) & 1u);   // RNE
  return (u16)(r >> 16);
}

__device__ __forceinline__ void gll16(const void* g, void* l) {
  __builtin_amdgcn_global_load_lds((const __attribute__((address_space(1))) void*)g,
                                   (__attribute__((address_space(3))) void*)l,
                                   16, 0, 0);
}

// ---------------- fp32 -> bf16 elementwise (x) ----------------
__global__ __launch_bounds__(256) void k_cvt(const float* __restrict__ in,
                                             u16* __restrict__ out) {
  int i = (blockIdx.x * 256 + threadIdx.x) * 8;
  float4 a = *(const float4*)(in + i);
  float4 b = *(const float4*)(in + i + 4);
  union { u16 u[8]; bf16x8 v; } r;
  r.u[0] = f2bf(a.x); r.u[1] = f2bf(a.y); r.u[2] = f2bf(a.z); r.u[3] = f2bf(a.w);
  r.u[4] = f2bf(b.x); r.u[5] = f2bf(b.y); r.u[6] = f2bf(b.z); r.u[7] = f2bf(b.w);
  *(bf16x8*)(out + i) = r.v;
}

// ------------- fp32 [K][N] -> bf16 [N][K] transpose -------------
__global__ __launch_bounds__(256) void k_cvtT(const float* __restrict__ in,
                                              u16* __restrict__ out, int K, int N) {
  __shared__ float tl[32][33];
  int tx = threadIdx.x & 31, ty = threadIdx.x >> 5;
  int c0 = blockIdx.x * 32, r0 = blockIdx.y * 32;
#pragma unroll
  for (int j = 0; j < 32; j += 8)
    tl[ty + j][tx] = in[(size_t)(r0 + ty + j) * N + c0 + tx];
  __syncthreads();
#pragma unroll
  for (int j = 0; j < 32; j += 8)
    out[(size_t)(c0 + ty + j) * K + r0 + tx] = f2bf(tl[tx][ty + j]);
}

// ---------------- bf16 GEMM: C = A[M][K] * BT[N][K]^T + bias ----------------
template<int OUT_BF16>
__global__ __launch_bounds__(256) void k_gemm(const u16* __restrict__ A,
                                              const u16* __restrict__ BT,
                                              const float* __restrict__ bias,
                                              void* __restrict__ Cv, int N, int K) {
  __shared__ alignas(16) u16 As[128 * 32];
  __shared__ alignas(16) u16 Bs[128 * 32];
  const int t = threadIdx.x, l = t & 63, w = t >> 6;
  const int brow = blockIdx.y * 128, bcol = blockIdx.x * 128;
  const int wr = w >> 1, wc = w & 1;
  f32x4 acc[4][4] = {};
  const u16* gA = A + (size_t)(brow + (t >> 2)) * K + (t & 3) * 8;
  const u16* gB = BT + (size_t)(bcol + (t >> 2)) * K + (t & 3) * 8;
  char* lA = (char*)As + w * 1024;
  char* lB = (char*)Bs + w * 1024;
  const int ro = (l & 15) * 64, ko = (l >> 4) * 16;
  for (int k0 = 0; k0 < K; k0 += 32) {
    gll16(gA + k0, lA);
    gll16(gA + (size_t)64 * K + k0, lA + 4096);
    gll16(gB + k0, lB);
    gll16(gB + (size_t)64 * K + k0, lB + 4096);
    __syncthreads();
    bf16x8 af[4], bff[4];
#pragma unroll
    for (int mi = 0; mi < 4; mi++)
      af[mi] = *(const bf16x8*)((const char*)As + (wr * 64 + mi * 16) * 64 + ro + ko);
#pragma unroll
    for (int ni = 0; ni < 4; ni++)
      bff[ni] = *(const bf16x8*)((const char*)Bs + (wc * 64 + ni * 16) * 64 + ro + ko);
#pragma unroll
    for (int mi = 0; mi < 4; mi++)
#pragma unroll
      for (int ni = 0; ni < 4; ni++)
        acc[mi][ni] = MFMA16(af[mi], bff[ni], acc[mi][ni]);
    __syncthreads();
  }
  const int r0 = brow + wr * 64 + (l >> 4) * 4;
  const int c0 = bcol + wc * 64 + (l & 15);
#pragma unroll
  for (int ni = 0; ni < 4; ni++) {
    float bv = bias[c0 + ni * 16];
#pragma unroll
    for (int mi = 0; mi < 4; mi++)
#pragma unroll
      for (int r = 0; r < 4; r++) {
        float v = acc[mi][ni][r] + bv;
        size_t off = (size_t)(r0 + mi * 16 + r) * N + c0 + ni * 16;
        if (OUT_BF16) ((u16*)Cv)[off] = f2bf(v);
        else          ((float*)Cv)[off] = v;
      }
  }
}

// -------- transpose V slice of qkv -> vT[bh][d][n] (bf16) --------
__global__ __launch_bounds__(256) void k_trV(const u16* __restrict__ qkv,
                                             u16* __restrict__ vT) {
  __shared__ u16 s[32][33];
  int tx = threadIdx.x & 31, ty = threadIdx.x >> 5;
  int n0 = blockIdx.x * 32, d0 = blockIdx.y * 32, bh = blockIdx.z;
  int b = bh >> 4, h = bh & 15;
#pragma unroll
  for (int j = 0; j < 32; j += 8)
    s[ty + j][tx] = qkv[(size_t)(b * SEQ + n0 + ty + j) * 3072 + 2048 + h * 64 + d0 + tx];
  __syncthreads();
#pragma unroll
  for (int j = 0; j < 32; j += 8)
    vT[(size_t)(bh * 64 + d0 + ty + j) * SEQ + n0 + tx] = s[tx][ty + j];
}

// ---------------- causal flash attention, v6 ----------------
// = R2's proven cross-lane primitives (__shfl_xor + cndmask exchange; NO
//   permlane inline asm -- unhandled VALU->permlane hazard suspected for NaN)
// + safe double-buffer: __syncthreads at top of iter, STAGE(j+1) after it
//   (DMA overlaps compute(j); barrier's full drain handles all hand-offs)
// + defer-max (THR=8, exp2 domain), vectorized exp2, max tree, setprio.
__global__ __launch_bounds__(256) void k_attn(const u16* __restrict__ qkv,
                                              const u16* __restrict__ vT,
                                              u16* __restrict__ outp) {
  __shared__ alignas(16) char SB[2][16384];   // per buffer: K [64][128B] | V [64][128B]
  const int t = threadIdx.x, l = t & 63, w = t >> 6;
  const int hi = l >> 5, q = l & 31;
  const int qp = blockIdx.x, h = blockIdx.y, b = blockIdx.z;
  const int bh = b * 16 + h;
  const int srow = t >> 3;                              // staging row 0..31
  const int csw = ((t & 7) * 16) ^ ((srow & 7) << 4);   // pre-swizzled source col (bytes)
  const int swz = (q & 7) << 4;                         // read-side XOR
  const float SC = 0.18033688011112042f;                // 0.125 * log2(e)

  auto STAGE = [&](char* buf, int kv0) {
    char* lK = buf + w * 1024;
    char* lV = buf + 8192 + w * 1024;
    gll16(qkv + (size_t)(b * SEQ + kv0 + srow) * 3072 + 1024 + h * 64 + (csw >> 1), lK);
    gll16(qkv + (size_t)(b * SEQ + kv0 + srow + 32) * 3072 + 1024 + h * 64 + (csw >> 1), lK + 4096);
    gll16(vT + (size_t)(bh * 64 + srow) * SEQ + kv0 + (csw >> 1), lV);
    gll16(vT + (size_t)(bh * 64 + srow + 32) * SEQ + kv0 + (csw >> 1), lV + 4096);
  };

  for (int tsel = 0; tsel < 2; tsel++) {
    const int qt = tsel ? (15 - qp) : qp;
    const int qr0 = qt * 128 + w * 32;
    const int qg = qr0 + q;
    bf16x8 qf[4];
#pragma unroll
    for (int c = 0; c < 4; c++)
      qf[c] = *(const bf16x8*)(qkv + (size_t)(b * SEQ + qg) * 3072 + h * 64 + c * 16 + hi * 8);
    f32x16 o0 = {}, o1 = {}, lv = {};
    float m_run = -1e30f;
    const int nkv = 2 * qt + 2;

    STAGE(SB[0], 0);
    for (int j = 0; j < nkv; j++) {
      const int kv0 = j * 64;
      __syncthreads();                       // tile j ready; prev readers retired
      if (j + 1 < nkv) STAGE(SB[(j + 1) & 1], kv0 + 64);   // DMA overlaps compute(j)
      const char* Kb = SB[j & 1];
      const char* Vb = Kb + 8192;

      if (kv0 <= qr0 + 31) {
        // ---- S^T = K . Q^T ----
        f32x16 st0 = {}, st1 = {};
        __builtin_amdgcn_s_setprio(1);
#pragma unroll
        for (int c = 0; c < 4; c++) {
          const int cb = c * 32 + hi * 16;
          bf16x8 k0 = *(const bf16x8*)(Kb + q * 128 + (cb ^ swz));
          bf16x8 k1 = *(const bf16x8*)(Kb + (32 + q) * 128 + (cb ^ swz));
          st0 = MFMA32(k0, qf[c], st0);
          st1 = MFMA32(k1, qf[c], st1);
        }
        __builtin_amdgcn_s_setprio(0);
        // ---- causal mask (raw domain) ----
        if (kv0 + 63 > qr0) {
#pragma unroll
          for (int r = 0; r < 16; r++) {
            const int krow = (r & 3) + 8 * (r >> 2) + 4 * hi;
            if (kv0 + krow > qg)      st0[r] = -1e30f;
            if (kv0 + 32 + krow > qg) st1[r] = -1e30f;
          }
        }
        // ---- tile max ----
        float tmx[16];
#pragma unroll
        for (int r = 0; r < 16; r++) tmx[r] = fmaxf(st0[r], st1[r]);
        float v0 = fmaxf(fmaxf(tmx[0], tmx[1]), tmx[2]);
        float v1 = fmaxf(fmaxf(tmx[3], tmx[4]), tmx[5]);
        float v2 = fmaxf(fmaxf(tmx[6], tmx[7]), tmx[8]);
        float v3 = fmaxf(fmaxf(tmx[9], tmx[10]), tmx[11]);
        float v4 = fmaxf(fmaxf(tmx[12], tmx[13]), tmx[14]);
        float v5 = fmaxf(fmaxf(v0, v1), tmx[15]);
        float v6 = fmaxf(fmaxf(v2, v3), v4);
        float v7 = fmaxf(v5, v6);
        const float vs = fmaxf(v7, __shfl_xor(v7, 32)) * SC;
        // ---- defer-max rescale ----
        if (__any(vs > m_run + 8.0f)) {
          float mnew = fmaxf(m_run, vs);
          float corr = EXP2F(m_run - mnew);
          m_run = mnew;
#pragma unroll
          for (int r = 0; r < 16; r++) { o0[r] *= corr; o1[r] *= corr; lv[r] *= corr; }
        }
        // ---- P = exp2(S*SC - m) ----
        f32x16 e0 = st0 * SC - m_run;
        f32x16 e1 = st1 * SC - m_run;
        f32x16 p0, p1;
#pragma unroll
        for (int r = 0; r < 16; r++) { p0[r] = EXP2F(e0[r]); p1[r] = EXP2F(e1[r]); }
        lv += p0 + p1;
        // ---- P^T -> bf16 B-frags (cvt_pk + shfl_xor exchange, R2-proven) ----
#pragma unroll
        for (int khb = 0; khb < 2; khb++) {
          uint32_t pk[8], ot[8];
#pragma unroll
          for (int ii = 0; ii < 8; ii++) {
            float lo = khb ? p1[2 * ii] : p0[2 * ii];
            float hf = khb ? p1[2 * ii + 1] : p0[2 * ii + 1];
            asm("v_cvt_pk_bf16_f32 %0, %1, %2" : "=v"(pk[ii]) : "v"(lo), "v"(hf));
          }
#pragma unroll
          for (int ii = 0; ii < 8; ii++) ot[ii] = (uint32_t)__shfl_xor((int)pk[ii], 32);
          union { uint32_t u[4]; bf16x8 v; } be, bo;
          be.u[0] = hi ? ot[2] : pk[0];
          be.u[1] = hi ? ot[3] : pk[1];
          be.u[2] = hi ? pk[2] : ot[0];
          be.u[3] = hi ? pk[3] : ot[1];
          bo.u[0] = hi ? ot[6] : pk[4];
          bo.u[1] = hi ? ot[7] : pk[5];
          bo.u[2] = hi ? pk[6] : ot[4];
          bo.u[3] = hi ? pk[7] : ot[5];
          __builtin_amdgcn_s_setprio(1);
#pragma unroll
          for (int kti = 0; kti < 2; kti++) {
            const int cb = (khb * 2 + kti) * 32 + hi * 16;
            bf16x8 vv0 = *(const bf16x8*)(Vb + q * 128 + (cb ^ swz));
            bf16x8 vv1 = *(const bf16x8*)(Vb + (32 + q) * 128 + (cb ^ swz));
            bf16x8 pb = kti ? bo.v : be.v;
            o0 = MFMA32(vv0, pb, o0);
            o1 = MFMA32(vv1, pb, o1);
          }
          __builtin_amdgcn_s_setprio(0);
        }
      }
    }
    __syncthreads();                          // last tile's readers retired before reuse
    // ---- epilogue ----
    float ls = ((lv[0] + lv[1]) + (lv[2] + lv[3])) + ((lv[4] + lv[5]) + (lv[6] + lv[7]))
             + ((lv[8] + lv[9]) + (lv[10] + lv[11])) + ((lv[12] + lv[13]) + (lv[14] + lv[15]));
    ls += __shfl_xor(ls, 32);
    const float invl = 1.0f / ls;
#pragma unroll
    for (int dh = 0; dh < 2; dh++)
#pragma unroll
      for (int jq = 0; jq < 4; jq++) {
        union { u16 u[4]; s16x4 v; } pk4;
#pragma unroll
        for (int r = 0; r < 4; r++)
          pk4.u[r] = f2bf((dh ? o1[4 * jq + r] : o0[4 * jq + r]) * invl);
        *(s16x4*)(outp + (size_t)(b * SEQ + qg) * 1024 + h * 64 + dh * 32 + jq * 8 + hi * 4) = pk4.v;
      }
  }
}

extern "C" void kernel_launch(void* const* d_in, const int* in_sizes, int n_in,
                              void* d_out, int out_size, void* d_ws, size_t ws_size,
                              hipStream_t stream) {
  const float* x     = (const float*)d_in[0];
  const float* w_qkv = (const float*)d_in[1];
  const float* b_qkv = (const float*)d_in[2];
  const float* w_out = (const float*)d_in[3];
  const float* b_out = (const float*)d_in[4];

  char* ws = (char*)d_ws;
  u16* xbf   = (u16*)(ws);                       // 16 MB [8192][1024]  (reused as attn_out)
  u16* wqkvT = (u16*)(ws + (16u << 20));         //  6 MB [3072][1024]
  u16* woutT = (u16*)(ws + (22u << 20));         //  2 MB [1024][1024]
  u16* qkvb  = (u16*)(ws + (24u << 20));         // 48 MB [8192][3072]
  u16* vTb   = (u16*)(ws + (72u << 20));         // 16 MB [64][64][2048]

  k_cvt <<<4096, 256, 0, stream>>>(x, xbf);
  k_cvtT<<<dim3(96, 32), 256, 0, stream>>>(w_qkv, wqkvT, 1024, 3072);
  k_cvtT<<<dim3(32, 32), 256, 0, stream>>>(w_out, woutT, 1024, 1024);
  k_gemm<1><<<dim3(24, 64), 256, 0, stream>>>(xbf, wqkvT, b_qkv, (void*)qkvb, 3072, 1024);
  k_trV <<<dim3(64, 2, 64), 256, 0, stream>>>(qkvb, vTb);
  k_attn<<<dim3(8, 16, 4), 256, 0, stream>>>(qkvb, vTb, xbf);
  k_gemm<0><<<dim3(8, 64), 256, 0, stream>>>(xbf, woutT, b_out, d_out, 1024, 1024);
}

// Round 7
// 202.168 us; speedup vs baseline: 1.8260x; 1.0596x over previous
//
#include <hip/hip_runtime.h>
#include <hip/hip_bf16.h>
#include <stdint.h>

typedef unsigned short u16;
typedef __attribute__((ext_vector_type(8))) short bf16x8;
typedef __attribute__((ext_vector_type(4))) float f32x4;
typedef __attribute__((ext_vector_type(16))) float f32x16;
typedef __attribute__((ext_vector_type(4))) short s16x4;

#define SEQ   2048
#define BATCH 4

#define MFMA16(a,b,c) __builtin_amdgcn_mfma_f32_16x16x32_bf16(a,b,c,0,0,0)
#define MFMA32(a,b,c) __builtin_amdgcn_mfma_f32_32x32x16_bf16(a,b,c,0,0,0)
#define EXP2F __builtin_amdgcn_exp2f

__device__ __forceinline__ u16 f2bf(float f) {
  union { float f; uint32_t u; } c{f};
  uint32_t r = c.u + 0x7fffu + ((c.u >> 16) & 1u);   // RNE
  return (u16)(r >> 16);
}

__device__ __forceinline__ void gll16(const void* g, void* l) {
  __builtin_amdgcn_global_load_lds((const __attribute__((address_space(1))) void*)g,
                                   (__attribute__((address_space(3))) void*)l,
                                   16, 0, 0);
}

// ---------------- fp32 -> bf16 elementwise (x) ----------------
__global__ __launch_bounds__(256) void k_cvt(const float* __restrict__ in,
                                             u16* __restrict__ out) {
  int i = (blockIdx.x * 256 + threadIdx.x) * 8;
  float4 a = *(const float4*)(in + i);
  float4 b = *(const float4*)(in + i + 4);
  union { u16 u[8]; bf16x8 v; } r;
  r.u[0] = f2bf(a.x); r.u[1] = f2bf(a.y); r.u[2] = f2bf(a.z); r.u[3] = f2bf(a.w);
  r.u[4] = f2bf(b.x); r.u[5] = f2bf(b.y); r.u[6] = f2bf(b.z); r.u[7] = f2bf(b.w);
  *(bf16x8*)(out + i) = r.v;
}

// ------------- fp32 [K][N] -> bf16 [N][K] transpose -------------
__global__ __launch_bounds__(256) void k_cvtT(const float* __restrict__ in,
                                              u16* __restrict__ out, int K, int N) {
  __shared__ float tl[32][33];
  int tx = threadIdx.x & 31, ty = threadIdx.x >> 5;
  int c0 = blockIdx.x * 32, r0 = blockIdx.y * 32;
#pragma unroll
  for (int j = 0; j < 32; j += 8)
    tl[ty + j][tx] = in[(size_t)(r0 + ty + j) * N + c0 + tx];
  __syncthreads();
#pragma unroll
  for (int j = 0; j < 32; j += 8)
    out[(size_t)(c0 + ty + j) * K + r0 + tx] = f2bf(tl[tx][ty + j]);
}

// ---------------- legacy 128x128 bf16 GEMM (kept for GEMM2) ----------------
template<int OUT_BF16>
__global__ __launch_bounds__(256) void k_gemm(const u16* __restrict__ A,
                                              const u16* __restrict__ BT,
                                              const float* __restrict__ bias,
                                              void* __restrict__ Cv, int N, int K) {
  __shared__ alignas(16) u16 As[128 * 32];
  __shared__ alignas(16) u16 Bs[128 * 32];
  const int t = threadIdx.x, l = t & 63, w = t >> 6;
  const int brow = blockIdx.y * 128, bcol = blockIdx.x * 128;
  const int wr = w >> 1, wc = w & 1;
  f32x4 acc[4][4] = {};
  const u16* gA = A + (size_t)(brow + (t >> 2)) * K + (t & 3) * 8;
  const u16* gB = BT + (size_t)(bcol + (t >> 2)) * K + (t & 3) * 8;
  char* lA = (char*)As + w * 1024;
  char* lB = (char*)Bs + w * 1024;
  const int ro = (l & 15) * 64, ko = (l >> 4) * 16;
  for (int k0 = 0; k0 < K; k0 += 32) {
    gll16(gA + k0, lA);
    gll16(gA + (size_t)64 * K + k0, lA + 4096);
    gll16(gB + k0, lB);
    gll16(gB + (size_t)64 * K + k0, lB + 4096);
    __syncthreads();
    bf16x8 af[4], bff[4];
#pragma unroll
    for (int mi = 0; mi < 4; mi++)
      af[mi] = *(const bf16x8*)((const char*)As + (wr * 64 + mi * 16) * 64 + ro + ko);
#pragma unroll
    for (int ni = 0; ni < 4; ni++)
      bff[ni] = *(const bf16x8*)((const char*)Bs + (wc * 64 + ni * 16) * 64 + ro + ko);
#pragma unroll
    for (int mi = 0; mi < 4; mi++)
#pragma unroll
      for (int ni = 0; ni < 4; ni++)
        acc[mi][ni] = MFMA16(af[mi], bff[ni], acc[mi][ni]);
    __syncthreads();
  }
  const int r0 = brow + wr * 64 + (l >> 4) * 4;
  const int c0 = bcol + wc * 64 + (l & 15);
#pragma unroll
  for (int ni = 0; ni < 4; ni++) {
    float bv = bias[c0 + ni * 16];
#pragma unroll
    for (int mi = 0; mi < 4; mi++)
#pragma unroll
      for (int r = 0; r < 4; r++) {
        float v = acc[mi][ni][r] + bv;
        size_t off = (size_t)(r0 + mi * 16 + r) * N + c0 + ni * 16;
        if (OUT_BF16) ((u16*)Cv)[off] = f2bf(v);
        else          ((float*)Cv)[off] = v;
      }
  }
}

// ============ 256x256 4-phase counted-vmcnt GEMM (T2+T3+T4+T5) ============
// C = A[M][K] * BT[N][K]^T + bias, bf16 out. 512 thr = 8 waves (2M x 4N),
// per-wave C 128x64 (M_rep 8, N_rep 4). BK=64. LDS 128KB = 2 buffers x
// {A:2 units, B:2 units}, unit = 16KB = 128 lds-rows x 64 bf16.
//   A unit mg: lds row = wm*64 + mi*16 + lr  <-> global row brow + wm*128 + mg*64 + ...
//   B unit ng: lds row = wn*32 + ni*16 + lr  <-> global row bcol + wn*64 + ng*32 + ...
// Row swizzle (T2): 16B col-group cg stored at cg ^ (row&7); staged via
// inverse-permuted global source (both-sides rule), read with same XOR -> 2-way = free.
// Phases per K-tile t (buf c=t&1), quadrant = (mg,ng), snake order w/ reg reuse:
//   p0: quad(0,0) reads A0,B0; stage A-mg0(t+1)->c^1   [freed end t-1 p3]
//   p1: quad(1,0) reads A1, B regs; stage B-ng0(t+2)->c [freed end t p0]; vmcnt(6)
//   p2: quad(1,1) reads B1, A regs; stage B-ng1(t+1)->c^1 [freed end t-1 p2]
//   p3: quad(0,1) re-reads A0, B regs; stage A-mg1(t+2)->c [freed end t p2]; vmcnt(6)
// Every phase ends: lgkmcnt(0) (drain my ds_reads) then raw s_barrier.
// vmcnt(6) = 3 units x 2 loads in flight; staged unit -> used 4 phases later.
// Prologue: 6 units in virtual-(t-2,t-1) order, then vmcnt(6)+barrier.
#define SBAR  asm volatile("s_barrier" ::: "memory")
#define LGKM0 asm volatile("s_waitcnt lgkmcnt(0)" ::: "memory")
#define VM6   asm volatile("s_waitcnt vmcnt(6)" ::: "memory")

__global__ __launch_bounds__(512, 2) void k_gemm256(const u16* __restrict__ A,
                                                    const u16* __restrict__ BT,
                                                    const float* __restrict__ bias,
                                                    u16* __restrict__ C,
                                                    int N, int K, int NT, int TN) {
  __shared__ alignas(16) char LDS[131072];
  const int t = threadIdx.x;
  const int l = t & 63, w = t >> 6;
  const int wm = w >> 2, wn = w & 3;
  const int lr = l & 15, lg = l >> 4;

  // XCD-aware bijective swizzle (nwg % 8 == 0 guaranteed by launch)
  const int nwg = gridDim.x;
  const int cpx = nwg >> 3;
  const int sb = (blockIdx.x & 7) * cpx + (blockIdx.x >> 3);
  const int brow = (sb / TN) * 256, bcol = (sb % TN) * 256;

  auto stageA = [&](int c, int mg, int tt) {
#pragma unroll
    for (int i = 0; i < 2; i++) {
      int s = t + i * 512;
      int r = s >> 3, cg = s & 7;
      int grow = brow + (r >> 6) * 128 + mg * 64 + (r & 63);
      int gk = tt * 64 + ((cg ^ (r & 7)) * 8);
      gll16(A + (size_t)grow * K + gk, LDS + c * 65536 + mg * 16384 + s * 16);
    }
  };
  auto stageB = [&](int c, int ng, int tt) {
#pragma unroll
    for (int i = 0; i < 2; i++) {
      int s = t + i * 512;
      int r = s >> 3, cg = s & 7;
      int grow = bcol + (r >> 5) * 64 + ng * 32 + (r & 31);
      int gk = tt * 64 + ((cg ^ (r & 7)) * 8);
      gll16(BT + (size_t)grow * K + gk, LDS + c * 65536 + 32768 + ng * 16384 + s * 16);
    }
  };

  f32x4 acc[8][4] = {};
  bf16x8 afr[2][4], bfr[2][2];

#define READ_A(c, mg)                                                          \
  {                                                                            \
    const char* baseA = LDS + (c) * 65536 + (mg) * 16384 + (wm * 64) * 128;    \
    _Pragma("unroll") for (int ks = 0; ks < 2; ks++)                           \
      _Pragma("unroll") for (int mi = 0; mi < 4; mi++)                         \
        afr[ks][mi] = *(const bf16x8*)(baseA + (mi * 16 + lr) * 128 +          \
                                       (((ks * 4 + lg) ^ (lr & 7)) * 16));     \
  }
#define READ_B(c, ng)                                                          \
  {                                                                            \
    const char* baseB = LDS + (c) * 65536 + 32768 + (ng) * 16384 + (wn * 32) * 128; \
    _Pragma("unroll") for (int ks = 0; ks < 2; ks++)                           \
      _Pragma("unroll") for (int ni = 0; ni < 2; ni++)                         \
        bfr[ks][ni] = *(const bf16x8*)(baseB + (ni * 16 + lr) * 128 +          \
                                       (((ks * 4 + lg) ^ (lr & 7)) * 16));     \
  }
#define DO_MFMA(MG, NG)                                                        \
  {                                                                            \
    __builtin_amdgcn_s_setprio(1);                                             \
    _Pragma("unroll") for (int ks = 0; ks < 2; ks++)                           \
      _Pragma("unroll") for (int mi = 0; mi < 4; mi++)                         \
        _Pragma("unroll") for (int ni = 0; ni < 2; ni++)                       \
          acc[(MG)*4 + mi][(NG)*2 + ni] =                                      \
              MFMA16(afr[ks][mi], bfr[ks][ni], acc[(MG)*4 + mi][(NG)*2 + ni]); \
    __builtin_amdgcn_s_setprio(0);                                             \
  }

  // ---- prologue: virtual t=-2 (p1,p3) then t=-1 (p0..p3) ----
  stageB(0, 0, 0);   // B-ng0(0)
  stageA(0, 1, 0);   // A-mg1(0)
  stageA(0, 0, 0);   // A-mg0(0)
  stageB(1, 0, 1);   // B-ng0(1)
  stageB(0, 1, 0);   // B-ng1(0)
  stageA(1, 1, 1);   // A-mg1(1)
  VM6; SBAR;

  for (int tt = 0; tt < NT; tt++) {
    const int c = tt & 1;
    // ---- p0: quad(mg0,ng0) ----
    if (tt + 1 < NT) stageA(c ^ 1, 0, tt + 1);
    READ_A(c, 0); READ_B(c, 0);
    DO_MFMA(0, 0);
    LGKM0; SBAR;
    // ---- p1: quad(mg1,ng0), B regs reused ----
    if (tt + 2 < NT) stageB(c, 0, tt + 2);
    READ_A(c, 1);
    DO_MFMA(1, 0);
    VM6; LGKM0; SBAR;
    // ---- p2: quad(mg1,ng1), A regs reused ----
    if (tt + 1 < NT) stageB(c ^ 1, 1, tt + 1);
    READ_B(c, 1);
    DO_MFMA(1, 1);
    LGKM0; SBAR;
    // ---- p3: quad(mg0,ng1), B regs reused, A0 re-read ----
    if (tt + 2 < NT) stageA(c, 1, tt + 2);
    READ_A(c, 0);
    DO_MFMA(0, 1);
    VM6; LGKM0; SBAR;
  }

  // ---- epilogue: bias + bf16 store ----
  const int r0 = brow + wm * 128 + (l >> 4) * 4;
  const int c0 = bcol + wn * 64 + (l & 15);
#pragma unroll
  for (int nig = 0; nig < 4; nig++) {
    float bv = bias[c0 + nig * 16];
#pragma unroll
    for (int mig = 0; mig < 8; mig++) {
      const int mg = mig >> 2, mi = mig & 3;
      const int row = r0 + mg * 64 + mi * 16;
#pragma unroll
      for (int r = 0; r < 4; r++)
        C[(size_t)(row + r) * N + c0 + nig * 16] = f2bf(acc[mig][nig][r] + bv);
    }
  }
}
#undef READ_A
#undef READ_B
#undef DO_MFMA

// -------- transpose V slice of qkv -> vT[bh][d][n] (bf16) --------
__global__ __launch_bounds__(256) void k_trV(const u16* __restrict__ qkv,
                                             u16* __restrict__ vT) {
  __shared__ u16 s[32][33];
  int tx = threadIdx.x & 31, ty = threadIdx.x >> 5;
  int n0 = blockIdx.x * 32, d0 = blockIdx.y * 32, bh = blockIdx.z;
  int b = bh >> 4, h = bh & 15;
#pragma unroll
  for (int j = 0; j < 32; j += 8)
    s[ty + j][tx] = qkv[(size_t)(b * SEQ + n0 + ty + j) * 3072 + 2048 + h * 64 + d0 + tx];
  __syncthreads();
#pragma unroll
  for (int j = 0; j < 32; j += 8)
    vT[(size_t)(bh * 64 + d0 + ty + j) * SEQ + n0 + tx] = s[tx][ty + j];
}

// ---------------- causal flash attention (v6, passing) ----------------
__global__ __launch_bounds__(256) void k_attn(const u16* __restrict__ qkv,
                                              const u16* __restrict__ vT,
                                              u16* __restrict__ outp) {
  __shared__ alignas(16) char SB[2][16384];   // per buffer: K [64][128B] | V [64][128B]
  const int t = threadIdx.x, l = t & 63, w = t >> 6;
  const int hi = l >> 5, q = l & 31;
  const int qp = blockIdx.x, h = blockIdx.y, b = blockIdx.z;
  const int bh = b * 16 + h;
  const int srow = t >> 3;
  const int csw = ((t & 7) * 16) ^ ((srow & 7) << 4);
  const int swz = (q & 7) << 4;
  const float SC = 0.18033688011112042f;                // 0.125 * log2(e)

  auto STAGE = [&](char* buf, int kv0) {
    char* lK = buf + w * 1024;
    char* lV = buf + 8192 + w * 1024;
    gll16(qkv + (size_t)(b * SEQ + kv0 + srow) * 3072 + 1024 + h * 64 + (csw >> 1), lK);
    gll16(qkv + (size_t)(b * SEQ + kv0 + srow + 32) * 3072 + 1024 + h * 64 + (csw >> 1), lK + 4096);
    gll16(vT + (size_t)(bh * 64 + srow) * SEQ + kv0 + (csw >> 1), lV);
    gll16(vT + (size_t)(bh * 64 + srow + 32) * SEQ + kv0 + (csw >> 1), lV + 4096);
  };

  for (int tsel = 0; tsel < 2; tsel++) {
    const int qt = tsel ? (15 - qp) : qp;
    const int qr0 = qt * 128 + w * 32;
    const int qg = qr0 + q;
    bf16x8 qf[4];
#pragma unroll
    for (int c = 0; c < 4; c++)
      qf[c] = *(const bf16x8*)(qkv + (size_t)(b * SEQ + qg) * 3072 + h * 64 + c * 16 + hi * 8);
    f32x16 o0 = {}, o1 = {}, lv = {};
    float m_run = -1e30f;
    const int nkv = 2 * qt + 2;

    STAGE(SB[0], 0);
    for (int j = 0; j < nkv; j++) {
      const int kv0 = j * 64;
      __syncthreads();
      if (j + 1 < nkv) STAGE(SB[(j + 1) & 1], kv0 + 64);
      const char* Kb = SB[j & 1];
      const char* Vb = Kb + 8192;

      if (kv0 <= qr0 + 31) {
        f32x16 st0 = {}, st1 = {};
        __builtin_amdgcn_s_setprio(1);
#pragma unroll
        for (int c = 0; c < 4; c++) {
          const int cb = c * 32 + hi * 16;
          bf16x8 k0 = *(const bf16x8*)(Kb + q * 128 + (cb ^ swz));
          bf16x8 k1 = *(const bf16x8*)(Kb + (32 + q) * 128 + (cb ^ swz));
          st0 = MFMA32(k0, qf[c], st0);
          st1 = MFMA32(k1, qf[c], st1);
        }
        __builtin_amdgcn_s_setprio(0);
        if (kv0 + 63 > qr0) {
#pragma unroll
          for (int r = 0; r < 16; r++) {
            const int krow = (r & 3) + 8 * (r >> 2) + 4 * hi;
            if (kv0 + krow > qg)      st0[r] = -1e30f;
            if (kv0 + 32 + krow > qg) st1[r] = -1e30f;
          }
        }
        float tmx[16];
#pragma unroll
        for (int r = 0; r < 16; r++) tmx[r] = fmaxf(st0[r], st1[r]);
        float v0 = fmaxf(fmaxf(tmx[0], tmx[1]), tmx[2]);
        float v1 = fmaxf(fmaxf(tmx[3], tmx[4]), tmx[5]);
        float v2 = fmaxf(fmaxf(tmx[6], tmx[7]), tmx[8]);
        float v3 = fmaxf(fmaxf(tmx[9], tmx[10]), tmx[11]);
        float v4 = fmaxf(fmaxf(tmx[12], tmx[13]), tmx[14]);
        float v5 = fmaxf(fmaxf(v0, v1), tmx[15]);
        float v6 = fmaxf(fmaxf(v2, v3), v4);
        float v7 = fmaxf(v5, v6);
        const float vs = fmaxf(v7, __shfl_xor(v7, 32)) * SC;
        if (__any(vs > m_run + 8.0f)) {
          float mnew = fmaxf(m_run, vs);
          float corr = EXP2F(m_run - mnew);
          m_run = mnew;
#pragma unroll
          for (int r = 0; r < 16; r++) { o0[r] *= corr; o1[r] *= corr; lv[r] *= corr; }
        }
        f32x16 e0 = st0 * SC - m_run;
        f32x16 e1 = st1 * SC - m_run;
        f32x16 p0, p1;
#pragma unroll
        for (int r = 0; r < 16; r++) { p0[r] = EXP2F(e0[r]); p1[r] = EXP2F(e1[r]); }
        lv += p0 + p1;
#pragma unroll
        for (int khb = 0; khb < 2; khb++) {
          uint32_t pk[8], ot[8];
#pragma unroll
          for (int ii = 0; ii < 8; ii++) {
            float lo = khb ? p1[2 * ii] : p0[2 * ii];
            float hf = khb ? p1[2 * ii + 1] : p0[2 * ii + 1];
            asm("v_cvt_pk_bf16_f32 %0, %1, %2" : "=v"(pk[ii]) : "v"(lo), "v"(hf));
          }
#pragma unroll
          for (int ii = 0; ii < 8; ii++) ot[ii] = (uint32_t)__shfl_xor((int)pk[ii], 32);
          union { uint32_t u[4]; bf16x8 v; } be, bo;
          be.u[0] = hi ? ot[2] : pk[0];
          be.u[1] = hi ? ot[3] : pk[1];
          be.u[2] = hi ? pk[2] : ot[0];
          be.u[3] = hi ? pk[3] : ot[1];
          bo.u[0] = hi ? ot[6] : pk[4];
          bo.u[1] = hi ? ot[7] : pk[5];
          bo.u[2] = hi ? pk[6] : ot[4];
          bo.u[3] = hi ? pk[7] : ot[5];
          __builtin_amdgcn_s_setprio(1);
#pragma unroll
          for (int kti = 0; kti < 2; kti++) {
            const int cb = (khb * 2 + kti) * 32 + hi * 16;
            bf16x8 vv0 = *(const bf16x8*)(Vb + q * 128 + (cb ^ swz));
            bf16x8 vv1 = *(const bf16x8*)(Vb + (32 + q) * 128 + (cb ^ swz));
            bf16x8 pb = kti ? bo.v : be.v;
            o0 = MFMA32(vv0, pb, o0);
            o1 = MFMA32(vv1, pb, o1);
          }
          __builtin_amdgcn_s_setprio(0);
        }
      }
    }
    __syncthreads();
    float ls = ((lv[0] + lv[1]) + (lv[2] + lv[3])) + ((lv[4] + lv[5]) + (lv[6] + lv[7]))
             + ((lv[8] + lv[9]) + (lv[10] + lv[11])) + ((lv[12] + lv[13]) + (lv[14] + lv[15]));
    ls += __shfl_xor(ls, 32);
    const float invl = 1.0f / ls;
#pragma unroll
    for (int dh = 0; dh < 2; dh++)
#pragma unroll
      for (int jq = 0; jq < 4; jq++) {
        union { u16 u[4]; s16x4 v; } pk4;
#pragma unroll
        for (int r = 0; r < 4; r++)
          pk4.u[r] = f2bf((dh ? o1[4 * jq + r] : o0[4 * jq + r]) * invl);
        *(s16x4*)(outp + (size_t)(b * SEQ + qg) * 1024 + h * 64 + dh * 32 + jq * 8 + hi * 4) = pk4.v;
      }
  }
}

extern "C" void kernel_launch(void* const* d_in, const int* in_sizes, int n_in,
                              void* d_out, int out_size, void* d_ws, size_t ws_size,
                              hipStream_t stream) {
  const float* x     = (const float*)d_in[0];
  const float* w_qkv = (const float*)d_in[1];
  const float* b_qkv = (const float*)d_in[2];
  const float* w_out = (const float*)d_in[3];
  const float* b_out = (const float*)d_in[4];

  char* ws = (char*)d_ws;
  u16* xbf   = (u16*)(ws);                       // 16 MB [8192][1024]  (reused as attn_out)
  u16* wqkvT = (u16*)(ws + (16u << 20));         //  6 MB [3072][1024]
  u16* woutT = (u16*)(ws + (22u << 20));         //  2 MB [1024][1024]
  u16* qkvb  = (u16*)(ws + (24u << 20));         // 48 MB [8192][3072]
  u16* vTb   = (u16*)(ws + (72u << 20));         // 16 MB [64][64][2048]

  k_cvt <<<4096, 256, 0, stream>>>(x, xbf);
  k_cvtT<<<dim3(96, 32), 256, 0, stream>>>(w_qkv, wqkvT, 1024, 3072);
  k_cvtT<<<dim3(32, 32), 256, 0, stream>>>(w_out, woutT, 1024, 1024);
  // GEMM1: M=8192, N=3072, K=1024 -> 32x12 = 384 tiles (384 % 8 == 0)
  k_gemm256<<<384, 512, 0, stream>>>(xbf, wqkvT, b_qkv, qkvb, 3072, 1024, 16, 12);
  k_trV <<<dim3(64, 2, 64), 256, 0, stream>>>(qkvb, vTb);
  k_attn<<<dim3(8, 16, 4), 256, 0, stream>>>(qkvb, vTb, xbf);
  k_gemm<0><<<dim3(8, 64), 256, 0, stream>>>(xbf, woutT, b_out, d_out, 1024, 1024);
}

// Round 8
// 196.748 us; speedup vs baseline: 1.8763x; 1.0275x over previous
//
#include <hip/hip_runtime.h>
#include <hip/hip_bf16.h>
#include <stdint.h>

typedef unsigned short u16;
typedef __attribute__((ext_vector_type(8))) short bf16x8;
typedef __attribute__((ext_vector_type(4))) float f32x4;
typedef __attribute__((ext_vector_type(16))) float f32x16;
typedef __attribute__((ext_vector_type(4))) short s16x4;

#define SEQ   2048
#define BATCH 4

#define MFMA16(a,b,c) __builtin_amdgcn_mfma_f32_16x16x32_bf16(a,b,c,0,0,0)
#define MFMA32(a,b,c) __builtin_amdgcn_mfma_f32_32x32x16_bf16(a,b,c,0,0,0)
#define EXP2F __builtin_amdgcn_exp2f

__device__ __forceinline__ u16 f2bf(float f) {
  union { float f; uint32_t u; } c{f};
  uint32_t r = c.u + 0x7fffu + ((c.u >> 16) & 1u);   // RNE
  return (u16)(r >> 16);
}

__device__ __forceinline__ void gll16(const void* g, void* l) {
  __builtin_amdgcn_global_load_lds((const __attribute__((address_space(1))) void*)g,
                                   (__attribute__((address_space(3))) void*)l,
                                   16, 0, 0);
}

// ---------------- fp32 -> bf16 elementwise (x) ----------------
__global__ __launch_bounds__(256) void k_cvt(const float* __restrict__ in,
                                             u16* __restrict__ out) {
  int i = (blockIdx.x * 256 + threadIdx.x) * 8;
  float4 a = *(const float4*)(in + i);
  float4 b = *(const float4*)(in + i + 4);
  union { u16 u[8]; bf16x8 v; } r;
  r.u[0] = f2bf(a.x); r.u[1] = f2bf(a.y); r.u[2] = f2bf(a.z); r.u[3] = f2bf(a.w);
  r.u[4] = f2bf(b.x); r.u[5] = f2bf(b.y); r.u[6] = f2bf(b.z); r.u[7] = f2bf(b.w);
  *(bf16x8*)(out + i) = r.v;
}

// ------------- fp32 [K][N] -> bf16 [N][K] transpose -------------
__global__ __launch_bounds__(256) void k_cvtT(const float* __restrict__ in,
                                              u16* __restrict__ out, int K, int N) {
  __shared__ float tl[32][33];
  int tx = threadIdx.x & 31, ty = threadIdx.x >> 5;
  int c0 = blockIdx.x * 32, r0 = blockIdx.y * 32;
#pragma unroll
  for (int j = 0; j < 32; j += 8)
    tl[ty + j][tx] = in[(size_t)(r0 + ty + j) * N + c0 + tx];
  __syncthreads();
#pragma unroll
  for (int j = 0; j < 32; j += 8)
    out[(size_t)(c0 + ty + j) * K + r0 + tx] = f2bf(tl[tx][ty + j]);
}

// ---------------- legacy 128x128 bf16 GEMM (kept for GEMM2) ----------------
template<int OUT_BF16>
__global__ __launch_bounds__(256) void k_gemm(const u16* __restrict__ A,
                                              const u16* __restrict__ BT,
                                              const float* __restrict__ bias,
                                              void* __restrict__ Cv, int N, int K) {
  __shared__ alignas(16) u16 As[128 * 32];
  __shared__ alignas(16) u16 Bs[128 * 32];
  const int t = threadIdx.x, l = t & 63, w = t >> 6;
  const int brow = blockIdx.y * 128, bcol = blockIdx.x * 128;
  const int wr = w >> 1, wc = w & 1;
  f32x4 acc[4][4] = {};
  const u16* gA = A + (size_t)(brow + (t >> 2)) * K + (t & 3) * 8;
  const u16* gB = BT + (size_t)(bcol + (t >> 2)) * K + (t & 3) * 8;
  char* lA = (char*)As + w * 1024;
  char* lB = (char*)Bs + w * 1024;
  const int ro = (l & 15) * 64, ko = (l >> 4) * 16;
  for (int k0 = 0; k0 < K; k0 += 32) {
    gll16(gA + k0, lA);
    gll16(gA + (size_t)64 * K + k0, lA + 4096);
    gll16(gB + k0, lB);
    gll16(gB + (size_t)64 * K + k0, lB + 4096);
    __syncthreads();
    bf16x8 af[4], bff[4];
#pragma unroll
    for (int mi = 0; mi < 4; mi++)
      af[mi] = *(const bf16x8*)((const char*)As + (wr * 64 + mi * 16) * 64 + ro + ko);
#pragma unroll
    for (int ni = 0; ni < 4; ni++)
      bff[ni] = *(const bf16x8*)((const char*)Bs + (wc * 64 + ni * 16) * 64 + ro + ko);
#pragma unroll
    for (int mi = 0; mi < 4; mi++)
#pragma unroll
      for (int ni = 0; ni < 4; ni++)
        acc[mi][ni] = MFMA16(af[mi], bff[ni], acc[mi][ni]);
    __syncthreads();
  }
  const int r0 = brow + wr * 64 + (l >> 4) * 4;
  const int c0 = bcol + wc * 64 + (l & 15);
#pragma unroll
  for (int ni = 0; ni < 4; ni++) {
    float bv = bias[c0 + ni * 16];
#pragma unroll
    for (int mi = 0; mi < 4; mi++)
#pragma unroll
      for (int r = 0; r < 4; r++) {
        float v = acc[mi][ni][r] + bv;
        size_t off = (size_t)(r0 + mi * 16 + r) * N + c0 + ni * 16;
        if (OUT_BF16) ((u16*)Cv)[off] = f2bf(v);
        else          ((float*)Cv)[off] = v;
      }
  }
}

// ============ 256x128 4-phase counted-vmcnt GEMM, balanced grid ============
// C = A[M][K]*BT[N][K]^T + bias, bf16 out. 512 thr = 8 waves (2 wm x 4 wn),
// per-wave C 128x32 (M_rep 8 over 2 mh-halves, N_rep 2). BK=64.
// LDS 96KB = 2 buf x {A-h0, A-h1, B} units of 16KB (128 lds-rows x 64 bf16).
//   A unit h: lds row r <-> global row brow + (r>>6)*128 + h*64 + (r&63)
//   B unit  : lds row r <-> global row bcol + r
// T2 swizzle: 16B col-group cg stored at cg^(row&7); staged via inverse-
// permuted global source; read with same XOR.
// Phases per K-tile t (buf c=t&1, stages -> c^1), snake (mh,ks) reuses B-frags:
//   p0 (h0,ks0): read A-h0,B(ks0); stage A-h0(t+1); vmcnt(2)*  [retires A-h1(t)]
//   p1 (h1,ks0): read A-h1; reuse B; stage B(t+1)
//   p2 (h1,ks1): read A-h1,B(ks1); stage A-h1(t+1)
//   p3 (h0,ks1): read A-h0; reuse B; vmcnt(2)  [retires A-h0(t+1)+B(t+1)]
// (*) at t=NT-1 p0 stages nothing -> outstanding==2 -> vmcnt(2) would no-op:
//     use vmcnt(0) there. Every phase ends lgkmcnt(0); s_barrier.
// Grid 32x24 = 768 = 3.0 blocks/CU balanced; 768%8==0 for XCD swizzle.
#define SBAR  asm volatile("s_barrier" ::: "memory")
#define LGKM0 asm volatile("s_waitcnt lgkmcnt(0)" ::: "memory")
#define VM2   asm volatile("s_waitcnt vmcnt(2)" ::: "memory")
#define VM0   asm volatile("s_waitcnt vmcnt(0)" ::: "memory")

__global__ __launch_bounds__(512, 2) void k_gemm256(const u16* __restrict__ A,
                                                    const u16* __restrict__ BT,
                                                    const float* __restrict__ bias,
                                                    u16* __restrict__ C,
                                                    int N, int K, int NT, int TN) {
  __shared__ alignas(16) char LDS[98304];
  const int t = threadIdx.x;
  const int l = t & 63, w = t >> 6;
  const int wm = w >> 2, wn = w & 3;
  const int lr = l & 15, lg = l >> 4;

  const int nwg = gridDim.x;
  const int cpx = nwg >> 3;
  const int sb = (blockIdx.x & 7) * cpx + (blockIdx.x >> 3);
  const int brow = (sb / TN) * 256, bcol = (sb % TN) * 128;

  auto stageA = [&](int c, int h, int tt) {
#pragma unroll
    for (int i = 0; i < 2; i++) {
      int s = t + i * 512;
      int r = s >> 3, cg = s & 7;
      int grow = brow + (r >> 6) * 128 + h * 64 + (r & 63);
      int gk = tt * 64 + ((cg ^ (r & 7)) * 8);
      gll16(A + (size_t)grow * K + gk, LDS + c * 49152 + h * 16384 + s * 16);
    }
  };
  auto stageB = [&](int c, int tt) {
#pragma unroll
    for (int i = 0; i < 2; i++) {
      int s = t + i * 512;
      int r = s >> 3, cg = s & 7;
      int grow = bcol + r;
      int gk = tt * 64 + ((cg ^ (r & 7)) * 8);
      gll16(BT + (size_t)grow * K + gk, LDS + c * 49152 + 32768 + s * 16);
    }
  };

  f32x4 acc[8][2] = {};
  bf16x8 afr[4], bfr[2];

#define READ_A(c, h, ks)                                                       \
  {                                                                            \
    const char* baseA = LDS + (c) * 49152 + (h) * 16384 + (wm * 64) * 128;     \
    _Pragma("unroll") for (int mi = 0; mi < 4; mi++)                           \
      afr[mi] = *(const bf16x8*)(baseA + (mi * 16 + lr) * 128 +                \
                                 ((((ks) * 4 + lg) ^ (lr & 7)) * 16));         \
  }
#define READ_B(c, ks)                                                          \
  {                                                                            \
    const char* baseB = LDS + (c) * 49152 + 32768 + (wn * 32) * 128;           \
    _Pragma("unroll") for (int ni = 0; ni < 2; ni++)                           \
      bfr[ni] = *(const bf16x8*)(baseB + (ni * 16 + lr) * 128 +                \
                                 ((((ks) * 4 + lg) ^ (lr & 7)) * 16));         \
  }
#define DO_MFMA(H)                                                             \
  {                                                                            \
    __builtin_amdgcn_s_setprio(1);                                             \
    _Pragma("unroll") for (int mi = 0; mi < 4; mi++)                           \
      _Pragma("unroll") for (int ni = 0; ni < 2; ni++)                         \
        acc[(H)*4 + mi][ni] = MFMA16(afr[mi], bfr[ni], acc[(H)*4 + mi][ni]);   \
    __builtin_amdgcn_s_setprio(0);                                             \
  }

  // ---- prologue: stage tile 0 (A-h0, B, A-h1); wait A-h0+B ----
  stageA(0, 0, 0);
  stageB(0, 0);
  stageA(0, 1, 0);
  VM2; SBAR;

  for (int tt = 0; tt < NT; tt++) {
    const int c = tt & 1;
    // ---- p0: (h0, ks0) ----
    if (tt + 1 < NT) { stageA(c ^ 1, 0, tt + 1); }
    READ_A(c, 0, 0); READ_B(c, 0);
    DO_MFMA(0);
    if (tt + 1 < NT) { VM2; } else { VM0; }   // retire A-h1(t)
    LGKM0; SBAR;
    // ---- p1: (h1, ks0), reuse B-frags ----
    if (tt + 1 < NT) { stageB(c ^ 1, tt + 1); }
    READ_A(c, 1, 0);
    DO_MFMA(1);
    LGKM0; SBAR;
    // ---- p2: (h1, ks1) ----
    if (tt + 1 < NT) { stageA(c ^ 1, 1, tt + 1); }
    READ_A(c, 1, 1); READ_B(c, 1);
    DO_MFMA(1);
    LGKM0; SBAR;
    // ---- p3: (h0, ks1), reuse B-frags ----
    READ_A(c, 0, 1);
    DO_MFMA(0);
    VM2;                                      // retire A-h0(t+1) + B(t+1)
    LGKM0; SBAR;
  }

  // ---- epilogue: bias + bf16 store ----
  const int r0 = brow + wm * 128 + lg * 4;
  const int c0 = bcol + wn * 32 + lr;
#pragma unroll
  for (int ni = 0; ni < 2; ni++) {
    float bv = bias[c0 + ni * 16];
#pragma unroll
    for (int mig = 0; mig < 8; mig++) {
      const int row = r0 + mig * 16;
#pragma unroll
      for (int r = 0; r < 4; r++)
        C[(size_t)(row + r) * N + c0 + ni * 16] = f2bf(acc[mig][ni][r] + bv);
    }
  }
}
#undef READ_A
#undef READ_B
#undef DO_MFMA

// -------- transpose V slice of qkv -> vT[bh][d][n] (bf16) --------
__global__ __launch_bounds__(256) void k_trV(const u16* __restrict__ qkv,
                                             u16* __restrict__ vT) {
  __shared__ u16 s[32][33];
  int tx = threadIdx.x & 31, ty = threadIdx.x >> 5;
  int n0 = blockIdx.x * 32, d0 = blockIdx.y * 32, bh = blockIdx.z;
  int b = bh >> 4, h = bh & 15;
#pragma unroll
  for (int j = 0; j < 32; j += 8)
    s[ty + j][tx] = qkv[(size_t)(b * SEQ + n0 + ty + j) * 3072 + 2048 + h * 64 + d0 + tx];
  __syncthreads();
#pragma unroll
  for (int j = 0; j < 32; j += 8)
    vT[(size_t)(bh * 64 + d0 + ty + j) * SEQ + n0 + tx] = s[tx][ty + j];
}

// ---------------- causal flash attention (v6, passing) ----------------
__global__ __launch_bounds__(256) void k_attn(const u16* __restrict__ qkv,
                                              const u16* __restrict__ vT,
                                              u16* __restrict__ outp) {
  __shared__ alignas(16) char SB[2][16384];   // per buffer: K [64][128B] | V [64][128B]
  const int t = threadIdx.x, l = t & 63, w = t >> 6;
  const int hi = l >> 5, q = l & 31;
  const int qp = blockIdx.x, h = blockIdx.y, b = blockIdx.z;
  const int bh = b * 16 + h;
  const int srow = t >> 3;
  const int csw = ((t & 7) * 16) ^ ((srow & 7) << 4);
  const int swz = (q & 7) << 4;
  const float SC = 0.18033688011112042f;                // 0.125 * log2(e)

  auto STAGE = [&](char* buf, int kv0) {
    char* lK = buf + w * 1024;
    char* lV = buf + 8192 + w * 1024;
    gll16(qkv + (size_t)(b * SEQ + kv0 + srow) * 3072 + 1024 + h * 64 + (csw >> 1), lK);
    gll16(qkv + (size_t)(b * SEQ + kv0 + srow + 32) * 3072 + 1024 + h * 64 + (csw >> 1), lK + 4096);
    gll16(vT + (size_t)(bh * 64 + srow) * SEQ + kv0 + (csw >> 1), lV);
    gll16(vT + (size_t)(bh * 64 + srow + 32) * SEQ + kv0 + (csw >> 1), lV + 4096);
  };

  for (int tsel = 0; tsel < 2; tsel++) {
    const int qt = tsel ? (15 - qp) : qp;
    const int qr0 = qt * 128 + w * 32;
    const int qg = qr0 + q;
    bf16x8 qf[4];
#pragma unroll
    for (int c = 0; c < 4; c++)
      qf[c] = *(const bf16x8*)(qkv + (size_t)(b * SEQ + qg) * 3072 + h * 64 + c * 16 + hi * 8);
    f32x16 o0 = {}, o1 = {}, lv = {};
    float m_run = -1e30f;
    const int nkv = 2 * qt + 2;

    STAGE(SB[0], 0);
    for (int j = 0; j < nkv; j++) {
      const int kv0 = j * 64;
      __syncthreads();
      if (j + 1 < nkv) STAGE(SB[(j + 1) & 1], kv0 + 64);
      const char* Kb = SB[j & 1];
      const char* Vb = Kb + 8192;

      if (kv0 <= qr0 + 31) {
        f32x16 st0 = {}, st1 = {};
        __builtin_amdgcn_s_setprio(1);
#pragma unroll
        for (int c = 0; c < 4; c++) {
          const int cb = c * 32 + hi * 16;
          bf16x8 k0 = *(const bf16x8*)(Kb + q * 128 + (cb ^ swz));
          bf16x8 k1 = *(const bf16x8*)(Kb + (32 + q) * 128 + (cb ^ swz));
          st0 = MFMA32(k0, qf[c], st0);
          st1 = MFMA32(k1, qf[c], st1);
        }
        __builtin_amdgcn_s_setprio(0);
        if (kv0 + 63 > qr0) {
#pragma unroll
          for (int r = 0; r < 16; r++) {
            const int krow = (r & 3) + 8 * (r >> 2) + 4 * hi;
            if (kv0 + krow > qg)      st0[r] = -1e30f;
            if (kv0 + 32 + krow > qg) st1[r] = -1e30f;
          }
        }
        float tmx[16];
#pragma unroll
        for (int r = 0; r < 16; r++) tmx[r] = fmaxf(st0[r], st1[r]);
        float v0 = fmaxf(fmaxf(tmx[0], tmx[1]), tmx[2]);
        float v1 = fmaxf(fmaxf(tmx[3], tmx[4]), tmx[5]);
        float v2 = fmaxf(fmaxf(tmx[6], tmx[7]), tmx[8]);
        float v3 = fmaxf(fmaxf(tmx[9], tmx[10]), tmx[11]);
        float v4 = fmaxf(fmaxf(tmx[12], tmx[13]), tmx[14]);
        float v5 = fmaxf(fmaxf(v0, v1), tmx[15]);
        float v6 = fmaxf(fmaxf(v2, v3), v4);
        float v7 = fmaxf(v5, v6);
        const float vs = fmaxf(v7, __shfl_xor(v7, 32)) * SC;
        if (__any(vs > m_run + 8.0f)) {
          float mnew = fmaxf(m_run, vs);
          float corr = EXP2F(m_run - mnew);
          m_run = mnew;
#pragma unroll
          for (int r = 0; r < 16; r++) { o0[r] *= corr; o1[r] *= corr; lv[r] *= corr; }
        }
        f32x16 e0 = st0 * SC - m_run;
        f32x16 e1 = st1 * SC - m_run;
        f32x16 p0, p1;
#pragma unroll
        for (int r = 0; r < 16; r++) { p0[r] = EXP2F(e0[r]); p1[r] = EXP2F(e1[r]); }
        lv += p0 + p1;
#pragma unroll
        for (int khb = 0; khb < 2; khb++) {
          uint32_t pk[8], ot[8];
#pragma unroll
          for (int ii = 0; ii < 8; ii++) {
            float lo = khb ? p1[2 * ii] : p0[2 * ii];
            float hf = khb ? p1[2 * ii + 1] : p0[2 * ii + 1];
            asm("v_cvt_pk_bf16_f32 %0, %1, %2" : "=v"(pk[ii]) : "v"(lo), "v"(hf));
          }
#pragma unroll
          for (int ii = 0; ii < 8; ii++) ot[ii] = (uint32_t)__shfl_xor((int)pk[ii], 32);
          union { uint32_t u[4]; bf16x8 v; } be, bo;
          be.u[0] = hi ? ot[2] : pk[0];
          be.u[1] = hi ? ot[3] : pk[1];
          be.u[2] = hi ? pk[2] : ot[0];
          be.u[3] = hi ? pk[3] : ot[1];
          bo.u[0] = hi ? ot[6] : pk[4];
          bo.u[1] = hi ? ot[7] : pk[5];
          bo.u[2] = hi ? pk[6] : ot[4];
          bo.u[3] = hi ? pk[7] : ot[5];
          __builtin_amdgcn_s_setprio(1);
#pragma unroll
          for (int kti = 0; kti < 2; kti++) {
            const int cb = (khb * 2 + kti) * 32 + hi * 16;
            bf16x8 vv0 = *(const bf16x8*)(Vb + q * 128 + (cb ^ swz));
            bf16x8 vv1 = *(const bf16x8*)(Vb + (32 + q) * 128 + (cb ^ swz));
            bf16x8 pb = kti ? bo.v : be.v;
            o0 = MFMA32(vv0, pb, o0);
            o1 = MFMA32(vv1, pb, o1);
          }
          __builtin_amdgcn_s_setprio(0);
        }
      }
    }
    __syncthreads();
    float ls = ((lv[0] + lv[1]) + (lv[2] + lv[3])) + ((lv[4] + lv[5]) + (lv[6] + lv[7]))
             + ((lv[8] + lv[9]) + (lv[10] + lv[11])) + ((lv[12] + lv[13]) + (lv[14] + lv[15]));
    ls += __shfl_xor(ls, 32);
    const float invl = 1.0f / ls;
#pragma unroll
    for (int dh = 0; dh < 2; dh++)
#pragma unroll
      for (int jq = 0; jq < 4; jq++) {
        union { u16 u[4]; s16x4 v; } pk4;
#pragma unroll
        for (int r = 0; r < 4; r++)
          pk4.u[r] = f2bf((dh ? o1[4 * jq + r] : o0[4 * jq + r]) * invl);
        *(s16x4*)(outp + (size_t)(b * SEQ + qg) * 1024 + h * 64 + dh * 32 + jq * 8 + hi * 4) = pk4.v;
      }
  }
}

extern "C" void kernel_launch(void* const* d_in, const int* in_sizes, int n_in,
                              void* d_out, int out_size, void* d_ws, size_t ws_size,
                              hipStream_t stream) {
  const float* x     = (const float*)d_in[0];
  const float* w_qkv = (const float*)d_in[1];
  const float* b_qkv = (const float*)d_in[2];
  const float* w_out = (const float*)d_in[3];
  const float* b_out = (const float*)d_in[4];

  char* ws = (char*)d_ws;
  u16* xbf   = (u16*)(ws);                       // 16 MB [8192][1024]  (reused as attn_out)
  u16* wqkvT = (u16*)(ws + (16u << 20));         //  6 MB [3072][1024]
  u16* woutT = (u16*)(ws + (22u << 20));         //  2 MB [1024][1024]
  u16* qkvb  = (u16*)(ws + (24u << 20));         // 48 MB [8192][3072]
  u16* vTb   = (u16*)(ws + (72u << 20));         // 16 MB [64][64][2048]

  k_cvt <<<4096, 256, 0, stream>>>(x, xbf);
  k_cvtT<<<dim3(96, 32), 256, 0, stream>>>(w_qkv, wqkvT, 1024, 3072);
  k_cvtT<<<dim3(32, 32), 256, 0, stream>>>(w_out, woutT, 1024, 1024);
  // GEMM1: M=8192, N=3072, K=1024 -> 32 x 24 = 768 tiles (3.0/CU, 768 % 8 == 0)
  k_gemm256<<<768, 512, 0, stream>>>(xbf, wqkvT, b_qkv, qkvb, 3072, 1024, 16, 24);
  k_trV <<<dim3(64, 2, 64), 256, 0, stream>>>(qkvb, vTb);
  k_attn<<<dim3(8, 16, 4), 256, 0, stream>>>(qkvb, vTb, xbf);
  k_gemm<0><<<dim3(8, 64), 256, 0, stream>>>(xbf, woutT, b_out, d_out, 1024, 1024);
}

// Round 9
// 185.659 us; speedup vs baseline: 1.9884x; 1.0597x over previous
//
#include <hip/hip_runtime.h>
#include <hip/hip_bf16.h>
#include <stdint.h>

typedef unsigned short u16;
typedef __attribute__((ext_vector_type(8))) short bf16x8;
typedef __attribute__((ext_vector_type(4))) float f32x4;
typedef __attribute__((ext_vector_type(16))) float f32x16;
typedef __attribute__((ext_vector_type(4))) short s16x4;
typedef __attribute__((ext_vector_type(2))) unsigned u32x2;

#define SEQ   2048
#define BATCH 4

#define MFMA16(a,b,c) __builtin_amdgcn_mfma_f32_16x16x32_bf16(a,b,c,0,0,0)
#define MFMA32(a,b,c) __builtin_amdgcn_mfma_f32_32x32x16_bf16(a,b,c,0,0,0)
#define EXP2F __builtin_amdgcn_exp2f

__device__ __forceinline__ u16 f2bf(float f) {
  union { float f; uint32_t u; } c{f};
  uint32_t r = c.u + 0x7fffu + ((c.u >> 16) & 1u);   // RNE
  return (u16)(r >> 16);
}

__device__ __forceinline__ void gll16(const void* g, void* l) {
  __builtin_amdgcn_global_load_lds((const __attribute__((address_space(1))) void*)g,
                                   (__attribute__((address_space(3))) void*)l,
                                   16, 0, 0);
}

// Builtin permlane32_swap (compiler-scoreboarded, unlike raw asm):
// returns {a' = {a_lo, b_lo}, b' = {a_hi, b_hi}} — exactly the R2-proven
// shfl_xor(32)+cndmask exchange.
__device__ __forceinline__ void plswap(uint32_t &a, uint32_t &b) {
  u32x2 r = __builtin_amdgcn_permlane32_swap(a, b, false, false);
  a = r[0]; b = r[1];
}
__device__ __forceinline__ float xhalf_max(float v) {
  union { float f; uint32_t u; } c{v};
  u32x2 r = __builtin_amdgcn_permlane32_swap(c.u, c.u, false, false);
  union { uint32_t u; float f; } x{r[0]}, y{r[1]};
  return fmaxf(x.f, y.f);
}
__device__ __forceinline__ float xhalf_add(float v) {
  union { float f; uint32_t u; } c{v};
  u32x2 r = __builtin_amdgcn_permlane32_swap(c.u, c.u, false, false);
  union { uint32_t u; float f; } x{r[0]}, y{r[1]};
  return x.f + y.f;
}

// ---------------- fp32 -> bf16 elementwise (x) ----------------
__global__ __launch_bounds__(256) void k_cvt(const float* __restrict__ in,
                                             u16* __restrict__ out) {
  int i = (blockIdx.x * 256 + threadIdx.x) * 8;
  float4 a = *(const float4*)(in + i);
  float4 b = *(const float4*)(in + i + 4);
  union { u16 u[8]; bf16x8 v; } r;
  r.u[0] = f2bf(a.x); r.u[1] = f2bf(a.y); r.u[2] = f2bf(a.z); r.u[3] = f2bf(a.w);
  r.u[4] = f2bf(b.x); r.u[5] = f2bf(b.y); r.u[6] = f2bf(b.z); r.u[7] = f2bf(b.w);
  *(bf16x8*)(out + i) = r.v;
}

// ------------- fp32 [K][N] -> bf16 [N][K] transpose -------------
__global__ __launch_bounds__(256) void k_cvtT(const float* __restrict__ in,
                                              u16* __restrict__ out, int K, int N) {
  __shared__ float tl[32][33];
  int tx = threadIdx.x & 31, ty = threadIdx.x >> 5;
  int c0 = blockIdx.x * 32, r0 = blockIdx.y * 32;
#pragma unroll
  for (int j = 0; j < 32; j += 8)
    tl[ty + j][tx] = in[(size_t)(r0 + ty + j) * N + c0 + tx];
  __syncthreads();
#pragma unroll
  for (int j = 0; j < 32; j += 8)
    out[(size_t)(c0 + ty + j) * K + r0 + tx] = f2bf(tl[tx][ty + j]);
}

// ============ 256x128 4-phase counted-vmcnt GEMM (R8-verified) ============
// OUT_F32: 0 -> bf16 C, 1 -> fp32 C. See R8 comments for schedule derivation.
#define SBAR  asm volatile("s_barrier" ::: "memory")
#define LGKM0 asm volatile("s_waitcnt lgkmcnt(0)" ::: "memory")
#define VM2   asm volatile("s_waitcnt vmcnt(2)" ::: "memory")
#define VM0   asm volatile("s_waitcnt vmcnt(0)" ::: "memory")

template<int OUT_F32>
__global__ __launch_bounds__(512, 2) void k_gemm256(const u16* __restrict__ A,
                                                    const u16* __restrict__ BT,
                                                    const float* __restrict__ bias,
                                                    void* __restrict__ Cv,
                                                    int N, int K, int NT, int TN) {
  __shared__ alignas(16) char LDS[98304];
  const int t = threadIdx.x;
  const int l = t & 63, w = t >> 6;
  const int wm = w >> 2, wn = w & 3;
  const int lr = l & 15, lg = l >> 4;

  const int nwg = gridDim.x;
  const int cpx = nwg >> 3;
  const int sb = (blockIdx.x & 7) * cpx + (blockIdx.x >> 3);
  const int brow = (sb / TN) * 256, bcol = (sb % TN) * 128;

  auto stageA = [&](int c, int h, int tt) {
#pragma unroll
    for (int i = 0; i < 2; i++) {
      int s = t + i * 512;
      int r = s >> 3, cg = s & 7;
      int grow = brow + (r >> 6) * 128 + h * 64 + (r & 63);
      int gk = tt * 64 + ((cg ^ (r & 7)) * 8);
      gll16(A + (size_t)grow * K + gk, LDS + c * 49152 + h * 16384 + s * 16);
    }
  };
  auto stageB = [&](int c, int tt) {
#pragma unroll
    for (int i = 0; i < 2; i++) {
      int s = t + i * 512;
      int r = s >> 3, cg = s & 7;
      int grow = bcol + r;
      int gk = tt * 64 + ((cg ^ (r & 7)) * 8);
      gll16(BT + (size_t)grow * K + gk, LDS + c * 49152 + 32768 + s * 16);
    }
  };

  f32x4 acc[8][2] = {};
  bf16x8 afr[4], bfr[2];

#define READ_A(c, h, ks)                                                       \
  {                                                                            \
    const char* baseA = LDS + (c) * 49152 + (h) * 16384 + (wm * 64) * 128;     \
    _Pragma("unroll") for (int mi = 0; mi < 4; mi++)                           \
      afr[mi] = *(const bf16x8*)(baseA + (mi * 16 + lr) * 128 +                \
                                 ((((ks) * 4 + lg) ^ (lr & 7)) * 16));         \
  }
#define READ_B(c, ks)                                                          \
  {                                                                            \
    const char* baseB = LDS + (c) * 49152 + 32768 + (wn * 32) * 128;           \
    _Pragma("unroll") for (int ni = 0; ni < 2; ni++)                           \
      bfr[ni] = *(const bf16x8*)(baseB + (ni * 16 + lr) * 128 +                \
                                 ((((ks) * 4 + lg) ^ (lr & 7)) * 16));         \
  }
#define DO_MFMA(H)                                                             \
  {                                                                            \
    __builtin_amdgcn_s_setprio(1);                                             \
    _Pragma("unroll") for (int mi = 0; mi < 4; mi++)                           \
      _Pragma("unroll") for (int ni = 0; ni < 2; ni++)                         \
        acc[(H)*4 + mi][ni] = MFMA16(afr[mi], bfr[ni], acc[(H)*4 + mi][ni]);   \
    __builtin_amdgcn_s_setprio(0);                                             \
  }

  stageA(0, 0, 0);
  stageB(0, 0);
  stageA(0, 1, 0);
  VM2; SBAR;

  for (int tt = 0; tt < NT; tt++) {
    const int c = tt & 1;
    if (tt + 1 < NT) { stageA(c ^ 1, 0, tt + 1); }
    READ_A(c, 0, 0); READ_B(c, 0);
    DO_MFMA(0);
    if (tt + 1 < NT) { VM2; } else { VM0; }
    LGKM0; SBAR;
    if (tt + 1 < NT) { stageB(c ^ 1, tt + 1); }
    READ_A(c, 1, 0);
    DO_MFMA(1);
    LGKM0; SBAR;
    if (tt + 1 < NT) { stageA(c ^ 1, 1, tt + 1); }
    READ_A(c, 1, 1); READ_B(c, 1);
    DO_MFMA(1);
    LGKM0; SBAR;
    READ_A(c, 0, 1);
    DO_MFMA(0);
    VM2;
    LGKM0; SBAR;
  }

  const int r0 = brow + wm * 128 + lg * 4;
  const int c0 = bcol + wn * 32 + lr;
#pragma unroll
  for (int ni = 0; ni < 2; ni++) {
    float bv = bias[c0 + ni * 16];
#pragma unroll
    for (int mig = 0; mig < 8; mig++) {
      const int row = r0 + mig * 16;
#pragma unroll
      for (int r = 0; r < 4; r++) {
        float v = acc[mig][ni][r] + bv;
        size_t off = (size_t)(row + r) * N + c0 + ni * 16;
        if (OUT_F32) ((float*)Cv)[off] = v;
        else         ((u16*)Cv)[off]   = f2bf(v);
      }
    }
  }
}
#undef READ_A
#undef READ_B
#undef DO_MFMA

// -------- transpose V slice of qkv -> vT[bh][d][n] (bf16) --------
__global__ __launch_bounds__(256) void k_trV(const u16* __restrict__ qkv,
                                             u16* __restrict__ vT) {
  __shared__ u16 s[32][33];
  int tx = threadIdx.x & 31, ty = threadIdx.x >> 5;
  int n0 = blockIdx.x * 32, d0 = blockIdx.y * 32, bh = blockIdx.z;
  int b = bh >> 4, h = bh & 15;
#pragma unroll
  for (int j = 0; j < 32; j += 8)
    s[ty + j][tx] = qkv[(size_t)(b * SEQ + n0 + ty + j) * 3072 + 2048 + h * 64 + d0 + tx];
  __syncthreads();
#pragma unroll
  for (int j = 0; j < 32; j += 8)
    vT[(size_t)(bh * 64 + d0 + ty + j) * SEQ + n0 + tx] = s[tx][ty + j];
}

// ---------------- causal flash attention, v7 ----------------
// = v6 with the P-exchange / cross-half reduces on the BUILTIN
//   permlane32_swap (mapping proven == v6's shfl+cndmask; builtin gets
//   compiler hazard handling that the R3 raw asm lacked).
__global__ __launch_bounds__(256) void k_attn(const u16* __restrict__ qkv,
                                              const u16* __restrict__ vT,
                                              u16* __restrict__ outp) {
  __shared__ alignas(16) char SB[2][16384];   // per buffer: K [64][128B] | V [64][128B]
  const int t = threadIdx.x, l = t & 63, w = t >> 6;
  const int hi = l >> 5, q = l & 31;
  const int qp = blockIdx.x, h = blockIdx.y, b = blockIdx.z;
  const int bh = b * 16 + h;
  const int srow = t >> 3;
  const int csw = ((t & 7) * 16) ^ ((srow & 7) << 4);
  const int swz = (q & 7) << 4;
  const float SC = 0.18033688011112042f;                // 0.125 * log2(e)

  auto STAGE = [&](char* buf, int kv0) {
    char* lK = buf + w * 1024;
    char* lV = buf + 8192 + w * 1024;
    gll16(qkv + (size_t)(b * SEQ + kv0 + srow) * 3072 + 1024 + h * 64 + (csw >> 1), lK);
    gll16(qkv + (size_t)(b * SEQ + kv0 + srow + 32) * 3072 + 1024 + h * 64 + (csw >> 1), lK + 4096);
    gll16(vT + (size_t)(bh * 64 + srow) * SEQ + kv0 + (csw >> 1), lV);
    gll16(vT + (size_t)(bh * 64 + srow + 32) * SEQ + kv0 + (csw >> 1), lV + 4096);
  };

  for (int tsel = 0; tsel < 2; tsel++) {
    const int qt = tsel ? (15 - qp) : qp;
    const int qr0 = qt * 128 + w * 32;
    const int qg = qr0 + q;
    bf16x8 qf[4];
#pragma unroll
    for (int c = 0; c < 4; c++)
      qf[c] = *(const bf16x8*)(qkv + (size_t)(b * SEQ + qg) * 3072 + h * 64 + c * 16 + hi * 8);
    f32x16 o0 = {}, o1 = {}, lv = {};
    float m_run = -1e30f;
    const int nkv = 2 * qt + 2;

    STAGE(SB[0], 0);
    for (int j = 0; j < nkv; j++) {
      const int kv0 = j * 64;
      __syncthreads();
      if (j + 1 < nkv) STAGE(SB[(j + 1) & 1], kv0 + 64);
      const char* Kb = SB[j & 1];
      const char* Vb = Kb + 8192;

      if (kv0 <= qr0 + 31) {
        f32x16 st0 = {}, st1 = {};
        __builtin_amdgcn_s_setprio(1);
#pragma unroll
        for (int c = 0; c < 4; c++) {
          const int cb = c * 32 + hi * 16;
          bf16x8 k0 = *(const bf16x8*)(Kb + q * 128 + (cb ^ swz));
          bf16x8 k1 = *(const bf16x8*)(Kb + (32 + q) * 128 + (cb ^ swz));
          st0 = MFMA32(k0, qf[c], st0);
          st1 = MFMA32(k1, qf[c], st1);
        }
        __builtin_amdgcn_s_setprio(0);
        if (kv0 + 63 > qr0) {
#pragma unroll
          for (int r = 0; r < 16; r++) {
            const int krow = (r & 3) + 8 * (r >> 2) + 4 * hi;
            if (kv0 + krow > qg)      st0[r] = -1e30f;
            if (kv0 + 32 + krow > qg) st1[r] = -1e30f;
          }
        }
        float tmx[16];
#pragma unroll
        for (int r = 0; r < 16; r++) tmx[r] = fmaxf(st0[r], st1[r]);
        float v0 = fmaxf(fmaxf(tmx[0], tmx[1]), tmx[2]);
        float v1 = fmaxf(fmaxf(tmx[3], tmx[4]), tmx[5]);
        float v2 = fmaxf(fmaxf(tmx[6], tmx[7]), tmx[8]);
        float v3 = fmaxf(fmaxf(tmx[9], tmx[10]), tmx[11]);
        float v4 = fmaxf(fmaxf(tmx[12], tmx[13]), tmx[14]);
        float v5 = fmaxf(fmaxf(v0, v1), tmx[15]);
        float v6 = fmaxf(fmaxf(v2, v3), v4);
        float v7 = fmaxf(v5, v6);
        const float vs = xhalf_max(v7) * SC;
        if (__any(vs > m_run + 8.0f)) {
          float mnew = fmaxf(m_run, vs);
          float corr = EXP2F(m_run - mnew);
          m_run = mnew;
#pragma unroll
          for (int r = 0; r < 16; r++) { o0[r] *= corr; o1[r] *= corr; lv[r] *= corr; }
        }
        f32x16 e0 = st0 * SC - m_run;
        f32x16 e1 = st1 * SC - m_run;
        f32x16 p0, p1;
#pragma unroll
        for (int r = 0; r < 16; r++) { p0[r] = EXP2F(e0[r]); p1[r] = EXP2F(e1[r]); }
        lv += p0 + p1;
        // ---- P^T -> bf16 B-frags via cvt_pk + builtin permlane32_swap ----
#pragma unroll
        for (int khb = 0; khb < 2; khb++) {
          uint32_t pk[8];
#pragma unroll
          for (int ii = 0; ii < 8; ii++) {
            float lo = khb ? p1[2 * ii] : p0[2 * ii];
            float hf = khb ? p1[2 * ii + 1] : p0[2 * ii + 1];
            asm("v_cvt_pk_bf16_f32 %0, %1, %2" : "=v"(pk[ii]) : "v"(lo), "v"(hf));
          }
          plswap(pk[0], pk[2]); plswap(pk[1], pk[3]);
          plswap(pk[4], pk[6]); plswap(pk[5], pk[7]);
          union { uint32_t u[4]; bf16x8 v; } be, bo;
          be.u[0] = pk[0]; be.u[1] = pk[1]; be.u[2] = pk[2]; be.u[3] = pk[3];
          bo.u[0] = pk[4]; bo.u[1] = pk[5]; bo.u[2] = pk[6]; bo.u[3] = pk[7];
          __builtin_amdgcn_s_setprio(1);
#pragma unroll
          for (int kti = 0; kti < 2; kti++) {
            const int cb = (khb * 2 + kti) * 32 + hi * 16;
            bf16x8 vv0 = *(const bf16x8*)(Vb + q * 128 + (cb ^ swz));
            bf16x8 vv1 = *(const bf16x8*)(Vb + (32 + q) * 128 + (cb ^ swz));
            bf16x8 pb = kti ? bo.v : be.v;
            o0 = MFMA32(vv0, pb, o0);
            o1 = MFMA32(vv1, pb, o1);
          }
          __builtin_amdgcn_s_setprio(0);
        }
      }
    }
    __syncthreads();
    float ls = ((lv[0] + lv[1]) + (lv[2] + lv[3])) + ((lv[4] + lv[5]) + (lv[6] + lv[7]))
             + ((lv[8] + lv[9]) + (lv[10] + lv[11])) + ((lv[12] + lv[13]) + (lv[14] + lv[15]));
    ls = xhalf_add(ls);
    const float invl = 1.0f / ls;
#pragma unroll
    for (int dh = 0; dh < 2; dh++)
#pragma unroll
      for (int jq = 0; jq < 4; jq++) {
        union { u16 u[4]; s16x4 v; } pk4;
#pragma unroll
        for (int r = 0; r < 4; r++)
          pk4.u[r] = f2bf((dh ? o1[4 * jq + r] : o0[4 * jq + r]) * invl);
        *(s16x4*)(outp + (size_t)(b * SEQ + qg) * 1024 + h * 64 + dh * 32 + jq * 8 + hi * 4) = pk4.v;
      }
  }
}

extern "C" void kernel_launch(void* const* d_in, const int* in_sizes, int n_in,
                              void* d_out, int out_size, void* d_ws, size_t ws_size,
                              hipStream_t stream) {
  const float* x     = (const float*)d_in[0];
  const float* w_qkv = (const float*)d_in[1];
  const float* b_qkv = (const float*)d_in[2];
  const float* w_out = (const float*)d_in[3];
  const float* b_out = (const float*)d_in[4];

  char* ws = (char*)d_ws;
  u16* xbf   = (u16*)(ws);                       // 16 MB [8192][1024]  (reused as attn_out)
  u16* wqkvT = (u16*)(ws + (16u << 20));         //  6 MB [3072][1024]
  u16* woutT = (u16*)(ws + (22u << 20));         //  2 MB [1024][1024]
  u16* qkvb  = (u16*)(ws + (24u << 20));         // 48 MB [8192][3072]
  u16* vTb   = (u16*)(ws + (72u << 20));         // 16 MB [64][64][2048]

  k_cvt <<<4096, 256, 0, stream>>>(x, xbf);
  k_cvtT<<<dim3(96, 32), 256, 0, stream>>>(w_qkv, wqkvT, 1024, 3072);
  k_cvtT<<<dim3(32, 32), 256, 0, stream>>>(w_out, woutT, 1024, 1024);
  // GEMM1: M=8192, N=3072 -> 32 x 24 = 768 blocks (3.0/CU)
  k_gemm256<0><<<768, 512, 0, stream>>>(xbf, wqkvT, b_qkv, qkvb, 3072, 1024, 16, 24);
  k_trV <<<dim3(64, 2, 64), 256, 0, stream>>>(qkvb, vTb);
  k_attn<<<dim3(8, 16, 4), 256, 0, stream>>>(qkvb, vTb, xbf);
  // GEMM2: M=8192, N=1024 -> 32 x 8 = 256 blocks (1.0/CU), fp32 out
  k_gemm256<1><<<256, 512, 0, stream>>>(xbf, woutT, b_out, d_out, 1024, 1024, 16, 8);
}

// Round 10
// 179.455 us; speedup vs baseline: 2.0571x; 1.0346x over previous
//
#include <hip/hip_runtime.h>
#include <hip/hip_bf16.h>
#include <stdint.h>

typedef unsigned short u16;
typedef __attribute__((ext_vector_type(8))) short bf16x8;
typedef __attribute__((ext_vector_type(4))) float f32x4;
typedef __attribute__((ext_vector_type(16))) float f32x16;
typedef __attribute__((ext_vector_type(4))) short s16x4;
typedef __attribute__((ext_vector_type(2))) unsigned u32x2;

#define SEQ   2048
#define BATCH 4

#define MFMA16(a,b,c) __builtin_amdgcn_mfma_f32_16x16x32_bf16(a,b,c,0,0,0)
#define MFMA32(a,b,c) __builtin_amdgcn_mfma_f32_32x32x16_bf16(a,b,c,0,0,0)
#define EXP2F __builtin_amdgcn_exp2f

__device__ __forceinline__ u16 f2bf(float f) {
  union { float f; uint32_t u; } c{f};
  uint32_t r = c.u + 0x7fffu + ((c.u >> 16) & 1u);   // RNE
  return (u16)(r >> 16);
}

__device__ __forceinline__ void gll16(const void* g, void* l) {
  __builtin_amdgcn_global_load_lds((const __attribute__((address_space(1))) void*)g,
                                   (__attribute__((address_space(3))) void*)l,
                                   16, 0, 0);
}

// Builtin permlane32_swap (compiler-scoreboarded):
__device__ __forceinline__ void plswap(uint32_t &a, uint32_t &b) {
  u32x2 r = __builtin_amdgcn_permlane32_swap(a, b, false, false);
  a = r[0]; b = r[1];
}
__device__ __forceinline__ float xhalf_max(float v) {
  union { float f; uint32_t u; } c{v};
  u32x2 r = __builtin_amdgcn_permlane32_swap(c.u, c.u, false, false);
  union { uint32_t u; float f; } x{r[0]}, y{r[1]};
  return fmaxf(x.f, y.f);
}
__device__ __forceinline__ float xhalf_add(float v) {
  union { float f; uint32_t u; } c{v};
  u32x2 r = __builtin_amdgcn_permlane32_swap(c.u, c.u, false, false);
  union { uint32_t u; float f; } x{r[0]}, y{r[1]};
  return x.f + y.f;
}

// ---------------- fp32 -> bf16 elementwise (x) ----------------
__global__ __launch_bounds__(256) void k_cvt(const float* __restrict__ in,
                                             u16* __restrict__ out) {
  int i = (blockIdx.x * 256 + threadIdx.x) * 8;
  float4 a = *(const float4*)(in + i);
  float4 b = *(const float4*)(in + i + 4);
  union { u16 u[8]; bf16x8 v; } r;
  r.u[0] = f2bf(a.x); r.u[1] = f2bf(a.y); r.u[2] = f2bf(a.z); r.u[3] = f2bf(a.w);
  r.u[4] = f2bf(b.x); r.u[5] = f2bf(b.y); r.u[6] = f2bf(b.z); r.u[7] = f2bf(b.w);
  *(bf16x8*)(out + i) = r.v;
}

// ------------- fp32 [K][N] -> bf16 [N][K] transpose -------------
__global__ __launch_bounds__(256) void k_cvtT(const float* __restrict__ in,
                                              u16* __restrict__ out, int K, int N) {
  __shared__ float tl[32][33];
  int tx = threadIdx.x & 31, ty = threadIdx.x >> 5;
  int c0 = blockIdx.x * 32, r0 = blockIdx.y * 32;
#pragma unroll
  for (int j = 0; j < 32; j += 8)
    tl[ty + j][tx] = in[(size_t)(r0 + ty + j) * N + c0 + tx];
  __syncthreads();
#pragma unroll
  for (int j = 0; j < 32; j += 8)
    out[(size_t)(c0 + ty + j) * K + r0 + tx] = f2bf(tl[tx][ty + j]);
}

// ============ 256x128 2-barrier counted-vmcnt GEMM (R8 template, v2) ============
// R8 schedule with interior barriers (end-p1, end-p2) DELETED after hazard
// re-audit: stages of tile t all go to buffer c^1; reads all from c (disjoint).
// Remaining sync per tile:
//   barrier #1 (after h0/ks0 MFMA):  VM2* retires A-h1(t)  -> p1 reads safe
//   barrier #2 (tile end): LGKM0 drains tile-t reads; VM2 retires A-h0(t+1)+B(t+1)
// vmcnt ledger (steady, 2 loads/unit): enter p0 with {A-h1(t)} out;
//   +A-h0(t+1) -> 4 -> VM2 retires A-h1(t); +B(t+1), +A-h1(t+1) -> 6
//   -> VM2 @end retires A-h0(t+1)+B(t+1) (issue order pinned by "" fences).
// Tail tt=NT-1: no stages; VM0 at barrier #1 retires A-h1(NT-1) (only 2 out).
// "" fences after each stage pin DMA issue order (rule: vmcnt counts oldest);
// MFMAs are register ops and schedule freely across them.
#define SBAR  asm volatile("s_barrier" ::: "memory")
#define LGKM0 asm volatile("s_waitcnt lgkmcnt(0)" ::: "memory")
#define VM2   asm volatile("s_waitcnt vmcnt(2)" ::: "memory")
#define VM0   asm volatile("s_waitcnt vmcnt(0)" ::: "memory")
#define FEN   asm volatile("" ::: "memory")

template<int OUT_F32>
__global__ __launch_bounds__(512, 2) void k_gemm256(const u16* __restrict__ A,
                                                    const u16* __restrict__ BT,
                                                    const float* __restrict__ bias,
                                                    void* __restrict__ Cv,
                                                    int N, int K, int NT, int TN) {
  __shared__ alignas(16) char LDS[98304];
  const int t = threadIdx.x;
  const int l = t & 63, w = t >> 6;
  const int wm = w >> 2, wn = w & 3;
  const int lr = l & 15, lg = l >> 4;

  const int nwg = gridDim.x;
  const int cpx = nwg >> 3;
  const int sb = (blockIdx.x & 7) * cpx + (blockIdx.x >> 3);
  const int brow = (sb / TN) * 256, bcol = (sb % TN) * 128;

  auto stageA = [&](int c, int h, int tt) {
#pragma unroll
    for (int i = 0; i < 2; i++) {
      int s = t + i * 512;
      int r = s >> 3, cg = s & 7;
      int grow = brow + (r >> 6) * 128 + h * 64 + (r & 63);
      int gk = tt * 64 + ((cg ^ (r & 7)) * 8);
      gll16(A + (size_t)grow * K + gk, LDS + c * 49152 + h * 16384 + s * 16);
    }
  };
  auto stageB = [&](int c, int tt) {
#pragma unroll
    for (int i = 0; i < 2; i++) {
      int s = t + i * 512;
      int r = s >> 3, cg = s & 7;
      int grow = bcol + r;
      int gk = tt * 64 + ((cg ^ (r & 7)) * 8);
      gll16(BT + (size_t)grow * K + gk, LDS + c * 49152 + 32768 + s * 16);
    }
  };

  f32x4 acc[8][2] = {};
  bf16x8 afr[4], bfr[2];

#define READ_A(c, h, ks)                                                       \
  {                                                                            \
    const char* baseA = LDS + (c) * 49152 + (h) * 16384 + (wm * 64) * 128;     \
    _Pragma("unroll") for (int mi = 0; mi < 4; mi++)                           \
      afr[mi] = *(const bf16x8*)(baseA + (mi * 16 + lr) * 128 +                \
                                 ((((ks) * 4 + lg) ^ (lr & 7)) * 16));         \
  }
#define READ_B(c, ks)                                                          \
  {                                                                            \
    const char* baseB = LDS + (c) * 49152 + 32768 + (wn * 32) * 128;           \
    _Pragma("unroll") for (int ni = 0; ni < 2; ni++)                           \
      bfr[ni] = *(const bf16x8*)(baseB + (ni * 16 + lr) * 128 +                \
                                 ((((ks) * 4 + lg) ^ (lr & 7)) * 16));         \
  }
#define DO_MFMA(H)                                                             \
  {                                                                            \
    __builtin_amdgcn_s_setprio(1);                                             \
    _Pragma("unroll") for (int mi = 0; mi < 4; mi++)                           \
      _Pragma("unroll") for (int ni = 0; ni < 2; ni++)                         \
        acc[(H)*4 + mi][ni] = MFMA16(afr[mi], bfr[ni], acc[(H)*4 + mi][ni]);   \
    __builtin_amdgcn_s_setprio(0);                                             \
  }

  // ---- prologue: stage tile 0; VM2 retires A-h0(0)+B(0), leaves A-h1(0) ----
  stageA(0, 0, 0); FEN;
  stageB(0, 0);    FEN;
  stageA(0, 1, 0); FEN;
  VM2; SBAR;

  for (int tt = 0; tt < NT; tt++) {
    const int c = tt & 1;
    // ---- p0: (h0, ks0) ----
    if (tt + 1 < NT) { stageA(c ^ 1, 0, tt + 1); FEN; }
    READ_A(c, 0, 0); READ_B(c, 0);
    DO_MFMA(0);
    if (tt + 1 < NT) { VM2; } else { VM0; }   // retire A-h1(t)
    LGKM0; SBAR;                               // barrier #1
    // ---- barrier-free zone: p1, p2, p3 ----
    if (tt + 1 < NT) { stageB(c ^ 1, tt + 1); FEN; }
    READ_A(c, 1, 0);
    DO_MFMA(1);                                // h1 ks0 (B-frags reused)
    if (tt + 1 < NT) { stageA(c ^ 1, 1, tt + 1); FEN; }
    READ_A(c, 1, 1); READ_B(c, 1);
    DO_MFMA(1);                                // h1 ks1
    READ_A(c, 0, 1);
    DO_MFMA(0);                                // h0 ks1 (B-frags reused)
    VM2;                                       // retire A-h0(t+1)+B(t+1)
    LGKM0; SBAR;                               // barrier #2 (tile handoff)
  }

  const int r0 = brow + wm * 128 + lg * 4;
  const int c0 = bcol + wn * 32 + lr;
#pragma unroll
  for (int ni = 0; ni < 2; ni++) {
    float bv = bias[c0 + ni * 16];
#pragma unroll
    for (int mig = 0; mig < 8; mig++) {
      const int row = r0 + mig * 16;
#pragma unroll
      for (int r = 0; r < 4; r++) {
        float v = acc[mig][ni][r] + bv;
        size_t off = (size_t)(row + r) * N + c0 + ni * 16;
        if (OUT_F32) ((float*)Cv)[off] = v;
        else         ((u16*)Cv)[off]   = f2bf(v);
      }
    }
  }
}
#undef READ_A
#undef READ_B
#undef DO_MFMA

// -------- transpose V slice of qkv -> vT[bh][d][n] (bf16) --------
__global__ __launch_bounds__(256) void k_trV(const u16* __restrict__ qkv,
                                             u16* __restrict__ vT) {
  __shared__ u16 s[32][33];
  int tx = threadIdx.x & 31, ty = threadIdx.x >> 5;
  int n0 = blockIdx.x * 32, d0 = blockIdx.y * 32, bh = blockIdx.z;
  int b = bh >> 4, h = bh & 15;
#pragma unroll
  for (int j = 0; j < 32; j += 8)
    s[ty + j][tx] = qkv[(size_t)(b * SEQ + n0 + ty + j) * 3072 + 2048 + h * 64 + d0 + tx];
  __syncthreads();
#pragma unroll
  for (int j = 0; j < 32; j += 8)
    vT[(size_t)(bh * 64 + d0 + ty + j) * SEQ + n0 + tx] = s[tx][ty + j];
}

// ---------------- causal flash attention (v7, passing) ----------------
__global__ __launch_bounds__(256) void k_attn(const u16* __restrict__ qkv,
                                              const u16* __restrict__ vT,
                                              u16* __restrict__ outp) {
  __shared__ alignas(16) char SB[2][16384];   // per buffer: K [64][128B] | V [64][128B]
  const int t = threadIdx.x, l = t & 63, w = t >> 6;
  const int hi = l >> 5, q = l & 31;
  const int qp = blockIdx.x, h = blockIdx.y, b = blockIdx.z;
  const int bh = b * 16 + h;
  const int srow = t >> 3;
  const int csw = ((t & 7) * 16) ^ ((srow & 7) << 4);
  const int swz = (q & 7) << 4;
  const float SC = 0.18033688011112042f;                // 0.125 * log2(e)

  auto STAGE = [&](char* buf, int kv0) {
    char* lK = buf + w * 1024;
    char* lV = buf + 8192 + w * 1024;
    gll16(qkv + (size_t)(b * SEQ + kv0 + srow) * 3072 + 1024 + h * 64 + (csw >> 1), lK);
    gll16(qkv + (size_t)(b * SEQ + kv0 + srow + 32) * 3072 + 1024 + h * 64 + (csw >> 1), lK + 4096);
    gll16(vT + (size_t)(bh * 64 + srow) * SEQ + kv0 + (csw >> 1), lV);
    gll16(vT + (size_t)(bh * 64 + srow + 32) * SEQ + kv0 + (csw >> 1), lV + 4096);
  };

  for (int tsel = 0; tsel < 2; tsel++) {
    const int qt = tsel ? (15 - qp) : qp;
    const int qr0 = qt * 128 + w * 32;
    const int qg = qr0 + q;
    bf16x8 qf[4];
#pragma unroll
    for (int c = 0; c < 4; c++)
      qf[c] = *(const bf16x8*)(qkv + (size_t)(b * SEQ + qg) * 3072 + h * 64 + c * 16 + hi * 8);
    f32x16 o0 = {}, o1 = {}, lv = {};
    float m_run = -1e30f;
    const int nkv = 2 * qt + 2;

    STAGE(SB[0], 0);
    for (int j = 0; j < nkv; j++) {
      const int kv0 = j * 64;
      __syncthreads();
      if (j + 1 < nkv) STAGE(SB[(j + 1) & 1], kv0 + 64);
      const char* Kb = SB[j & 1];
      const char* Vb = Kb + 8192;

      if (kv0 <= qr0 + 31) {
        f32x16 st0 = {}, st1 = {};
        __builtin_amdgcn_s_setprio(1);
#pragma unroll
        for (int c = 0; c < 4; c++) {
          const int cb = c * 32 + hi * 16;
          bf16x8 k0 = *(const bf16x8*)(Kb + q * 128 + (cb ^ swz));
          bf16x8 k1 = *(const bf16x8*)(Kb + (32 + q) * 128 + (cb ^ swz));
          st0 = MFMA32(k0, qf[c], st0);
          st1 = MFMA32(k1, qf[c], st1);
        }
        __builtin_amdgcn_s_setprio(0);
        if (kv0 + 63 > qr0) {
#pragma unroll
          for (int r = 0; r < 16; r++) {
            const int krow = (r & 3) + 8 * (r >> 2) + 4 * hi;
            if (kv0 + krow > qg)      st0[r] = -1e30f;
            if (kv0 + 32 + krow > qg) st1[r] = -1e30f;
          }
        }
        float tmx[16];
#pragma unroll
        for (int r = 0; r < 16; r++) tmx[r] = fmaxf(st0[r], st1[r]);
        float v0 = fmaxf(fmaxf(tmx[0], tmx[1]), tmx[2]);
        float v1 = fmaxf(fmaxf(tmx[3], tmx[4]), tmx[5]);
        float v2 = fmaxf(fmaxf(tmx[6], tmx[7]), tmx[8]);
        float v3 = fmaxf(fmaxf(tmx[9], tmx[10]), tmx[11]);
        float v4 = fmaxf(fmaxf(tmx[12], tmx[13]), tmx[14]);
        float v5 = fmaxf(fmaxf(v0, v1), tmx[15]);
        float v6 = fmaxf(fmaxf(v2, v3), v4);
        float v7 = fmaxf(v5, v6);
        const float vs = xhalf_max(v7) * SC;
        if (__any(vs > m_run + 8.0f)) {
          float mnew = fmaxf(m_run, vs);
          float corr = EXP2F(m_run - mnew);
          m_run = mnew;
#pragma unroll
          for (int r = 0; r < 16; r++) { o0[r] *= corr; o1[r] *= corr; lv[r] *= corr; }
        }
        f32x16 e0 = st0 * SC - m_run;
        f32x16 e1 = st1 * SC - m_run;
        f32x16 p0, p1;
#pragma unroll
        for (int r = 0; r < 16; r++) { p0[r] = EXP2F(e0[r]); p1[r] = EXP2F(e1[r]); }
        lv += p0 + p1;
#pragma unroll
        for (int khb = 0; khb < 2; khb++) {
          uint32_t pk[8];
#pragma unroll
          for (int ii = 0; ii < 8; ii++) {
            float lo = khb ? p1[2 * ii] : p0[2 * ii];
            float hf = khb ? p1[2 * ii + 1] : p0[2 * ii + 1];
            asm("v_cvt_pk_bf16_f32 %0, %1, %2" : "=v"(pk[ii]) : "v"(lo), "v"(hf));
          }
          plswap(pk[0], pk[2]); plswap(pk[1], pk[3]);
          plswap(pk[4], pk[6]); plswap(pk[5], pk[7]);
          union { uint32_t u[4]; bf16x8 v; } be, bo;
          be.u[0] = pk[0]; be.u[1] = pk[1]; be.u[2] = pk[2]; be.u[3] = pk[3];
          bo.u[0] = pk[4]; bo.u[1] = pk[5]; bo.u[2] = pk[6]; bo.u[3] = pk[7];
          __builtin_amdgcn_s_setprio(1);
#pragma unroll
          for (int kti = 0; kti < 2; kti++) {
            const int cb = (khb * 2 + kti) * 32 + hi * 16;
            bf16x8 vv0 = *(const bf16x8*)(Vb + q * 128 + (cb ^ swz));
            bf16x8 vv1 = *(const bf16x8*)(Vb + (32 + q) * 128 + (cb ^ swz));
            bf16x8 pb = kti ? bo.v : be.v;
            o0 = MFMA32(vv0, pb, o0);
            o1 = MFMA32(vv1, pb, o1);
          }
          __builtin_amdgcn_s_setprio(0);
        }
      }
    }
    __syncthreads();
    float ls = ((lv[0] + lv[1]) + (lv[2] + lv[3])) + ((lv[4] + lv[5]) + (lv[6] + lv[7]))
             + ((lv[8] + lv[9]) + (lv[10] + lv[11])) + ((lv[12] + lv[13]) + (lv[14] + lv[15]));
    ls = xhalf_add(ls);
    const float invl = 1.0f / ls;
#pragma unroll
    for (int dh = 0; dh < 2; dh++)
#pragma unroll
      for (int jq = 0; jq < 4; jq++) {
        union { u16 u[4]; s16x4 v; } pk4;
#pragma unroll
        for (int r = 0; r < 4; r++)
          pk4.u[r] = f2bf((dh ? o1[4 * jq + r] : o0[4 * jq + r]) * invl);
        *(s16x4*)(outp + (size_t)(b * SEQ + qg) * 1024 + h * 64 + dh * 32 + jq * 8 + hi * 4) = pk4.v;
      }
  }
}

extern "C" void kernel_launch(void* const* d_in, const int* in_sizes, int n_in,
                              void* d_out, int out_size, void* d_ws, size_t ws_size,
                              hipStream_t stream) {
  const float* x     = (const float*)d_in[0];
  const float* w_qkv = (const float*)d_in[1];
  const float* b_qkv = (const float*)d_in[2];
  const float* w_out = (const float*)d_in[3];
  const float* b_out = (const float*)d_in[4];

  char* ws = (char*)d_ws;
  u16* xbf   = (u16*)(ws);                       // 16 MB [8192][1024]  (reused as attn_out)
  u16* wqkvT = (u16*)(ws + (16u << 20));         //  6 MB [3072][1024]
  u16* woutT = (u16*)(ws + (22u << 20));         //  2 MB [1024][1024]
  u16* qkvb  = (u16*)(ws + (24u << 20));         // 48 MB [8192][3072]
  u16* vTb   = (u16*)(ws + (72u << 20));         // 16 MB [64][64][2048]

  k_cvt <<<4096, 256, 0, stream>>>(x, xbf);
  k_cvtT<<<dim3(96, 32), 256, 0, stream>>>(w_qkv, wqkvT, 1024, 3072);
  k_cvtT<<<dim3(32, 32), 256, 0, stream>>>(w_out, woutT, 1024, 1024);
  // GEMM1: M=8192, N=3072 -> 32 x 24 = 768 blocks (3.0/CU)
  k_gemm256<0><<<768, 512, 0, stream>>>(xbf, wqkvT, b_qkv, qkvb, 3072, 1024, 16, 24);
  k_trV <<<dim3(64, 2, 64), 256, 0, stream>>>(qkvb, vTb);
  k_attn<<<dim3(8, 16, 4), 256, 0, stream>>>(qkvb, vTb, xbf);
  // GEMM2: M=8192, N=1024 -> 32 x 8 = 256 blocks (1.0/CU), fp32 out
  k_gemm256<1><<<256, 512, 0, stream>>>(xbf, woutT, b_out, d_out, 1024, 1024, 16, 8);
}